// Round 1
// baseline (685.693 us; speedup 1.0000x reference)
//
#include <hip/hip_runtime.h>
#include <hip/hip_bf16.h>
#include <math.h>

typedef __bf16 bf16_t;
typedef __bf16 bf16x4 __attribute__((ext_vector_type(4)));
typedef __bf16 bf16x8 __attribute__((ext_vector_type(8)));
typedef float floatx4 __attribute__((ext_vector_type(4)));

#define MFMA16(a, b, c) __builtin_amdgcn_mfma_f32_16x16x32_bf16((a), (b), (c), 0, 0, 0)

#define NEG_BIG (-1e30f)

// async global->LDS, 16B per lane; lds dest = wave-uniform base + lane*16
__device__ __forceinline__ void gload16(const bf16_t* g, bf16_t* l) {
    __builtin_amdgcn_global_load_lds(
        (const __attribute__((address_space(1))) unsigned int*)g,
        (__attribute__((address_space(3))) unsigned int*)l,
        16, 0, 0);
}

// ---------------------------------------------------------------------------
// Detect input dtype: q_a_ln_w is all ones. fp32 word0 = 0x3F800000,
// bf16-packed word0 = 0x3F803F80. flag=1 -> bf16, flag=0 -> fp32.
// ---------------------------------------------------------------------------
__global__ void detect_kernel(const unsigned int* __restrict__ lnw, int* __restrict__ flag) {
    if (threadIdx.x == 0 && blockIdx.x == 0)
        flag[0] = (lnw[0] == 0x3F803F80u) ? 1 : 0;
}

__global__ __launch_bounds__(256) void conv_in_kernel(const void* __restrict__ src,
                                                      bf16_t* __restrict__ dst,
                                                      long nchunk,
                                                      const int* __restrict__ flag) {
    long i = (long)blockIdx.x * 256 + threadIdx.x;
    if (i >= nchunk) return;
    if (flag[0]) {
        ((uint4*)dst)[i] = ((const uint4*)src)[i];
    } else {
        const float* f = (const float*)src + i * 8;
        bf16x8 o;
#pragma unroll
        for (int j = 0; j < 8; ++j) o[j] = (bf16_t)f[j];
        ((bf16x8*)dst)[i] = o;
    }
}

// conv with scalar multiply (used to fold softmax scale into wq_b)
__global__ __launch_bounds__(256) void conv_in_scale_kernel(const void* __restrict__ src,
                                                            bf16_t* __restrict__ dst,
                                                            long nchunk,
                                                            const int* __restrict__ flag,
                                                            float s) {
    long i = (long)blockIdx.x * 256 + threadIdx.x;
    if (i >= nchunk) return;
    bf16x8 o;
    if (flag[0]) {
        bf16x8 v = ((const bf16x8*)src)[i];
#pragma unroll
        for (int j = 0; j < 8; ++j) o[j] = (bf16_t)((float)v[j] * s);
    } else {
        const float* f = (const float*)src + i * 8;
#pragma unroll
        for (int j = 0; j < 8; ++j) o[j] = (bf16_t)(f[j] * s);
    }
    ((bf16x8*)dst)[i] = o;
}

__global__ __launch_bounds__(256) void conv_out_kernel(const bf16_t* __restrict__ src,
                                                       void* __restrict__ dst,
                                                       long nchunk,
                                                       const int* __restrict__ flag) {
    long i = (long)blockIdx.x * 256 + threadIdx.x;
    if (i >= nchunk) return;
    bf16x8 v = ((const bf16x8*)src)[i];
    if (flag[0]) {
        ((uint4*)dst)[i] = *(const uint4*)&v;
    } else {
        float* f = (float*)dst + i * 8;
#pragma unroll
        for (int j = 0; j < 8; ++j) f[j] = (float)v[j];
    }
}

__global__ __launch_bounds__(256) void pad_wkv_kernel(const void* __restrict__ src,
                                                      bf16_t* __restrict__ dst,
                                                      const int* __restrict__ flag) {
    long idx = (long)blockIdx.x * 256 + threadIdx.x;
    long e0 = idx * 8;
    if (e0 >= (long)640 * 2048) return;
    int row = (int)(e0 >> 11);
    bf16x8 v;
#pragma unroll
    for (int j = 0; j < 8; ++j) v[j] = (bf16_t)0.0f;
    if (row < 576) {
        if (flag[0]) {
            v = *(const bf16x8*)((const bf16_t*)src + e0);
        } else {
            const float* f = (const float*)src + e0;
#pragma unroll
            for (int j = 0; j < 8; ++j) v[j] = (bf16_t)f[j];
        }
    }
    *(bf16x8*)(dst + e0) = v;
}

// ---------------------------------------------------------------------------
// GEMM (m97 structure): C[M,N] = A[M,K] @ B[N,K]^T, bf16, fp32 acc.
// 128x128 tile, BK=32, async global_load_lds width-16 staging, unpadded LDS.
// ---------------------------------------------------------------------------
__global__ __launch_bounds__(256) void gemm_bf16(const bf16_t* __restrict__ A,
                                                 const bf16_t* __restrict__ B,
                                                 bf16_t* __restrict__ C,
                                                 int M, int N, int K) {
    __shared__ __align__(16) bf16_t As[128 * 32];
    __shared__ __align__(16) bf16_t Bs[128 * 32];

    int tid = threadIdx.x;
    int lane = tid & 63;
    int wave = tid >> 6;
    int m0 = blockIdx.x * 128;
    int n0 = blockIdx.y * 128;
    int wm = (wave & 1) * 64;
    int wn = (wave >> 1) * 64;
    int col = lane & 15;
    int g = lane >> 4;

    floatx4 acc[4][4] = {};

    // staging: wave w covers rows [w*32, w*32+32) via two 16-row async calls
    int srow = wave * 32 + (lane >> 2);
    int scol = (lane & 3) * 8;
    const bf16_t* Ag = A + (size_t)(m0 + srow) * K + scol;
    const bf16_t* Bg = B + (size_t)(n0 + srow) * K + scol;
    bf16_t* AsW0 = &As[(wave * 2 + 0) * 512];
    bf16_t* AsW1 = &As[(wave * 2 + 1) * 512];
    bf16_t* BsW0 = &Bs[(wave * 2 + 0) * 512];
    bf16_t* BsW1 = &Bs[(wave * 2 + 1) * 512];
    size_t r16 = (size_t)16 * K;

    for (int kk = K >> 5; kk > 0; --kk) {
        __syncthreads();
        gload16(Ag, AsW0);
        gload16(Ag + r16, AsW1);
        gload16(Bg, BsW0);
        gload16(Bg + r16, BsW1);
        Ag += 32; Bg += 32;
        __syncthreads();

        bf16x8 af[4], bfr[4];
#pragma unroll
        for (int i = 0; i < 4; ++i) af[i] = *(const bf16x8*)(&As[(wm + i * 16 + col) * 32 + g * 8]);
#pragma unroll
        for (int j = 0; j < 4; ++j) bfr[j] = *(const bf16x8*)(&Bs[(wn + j * 16 + col) * 32 + g * 8]);
#pragma unroll
        for (int i = 0; i < 4; ++i)
#pragma unroll
            for (int j = 0; j < 4; ++j)
                acc[i][j] = MFMA16(af[i], bfr[j], acc[i][j]);
    }

#pragma unroll
    for (int i = 0; i < 4; ++i)
#pragma unroll
        for (int j = 0; j < 4; ++j) {
            size_t mrow = (size_t)(m0 + wm + i * 16 + g * 4);
            size_t ncol = (size_t)(n0 + wn + j * 16 + col);
            bf16_t* cp = C + mrow * N + ncol;
#pragma unroll
            for (int r = 0; r < 4; ++r) cp[(size_t)r * N] = (bf16_t)acc[i][j][r];
        }
}

// ---------------------------------------------------------------------------
// kv GEMM (m97 staging) with split epilogue:
//   k_nope -> kn[tok][16*128],  v -> vT[b][h][128 d][2048 s]
// ---------------------------------------------------------------------------
__global__ __launch_bounds__(256) void gemm_kv(const bf16_t* __restrict__ A,
                                               const bf16_t* __restrict__ B,
                                               bf16_t* __restrict__ kn,
                                               bf16_t* __restrict__ vT,
                                               int K) {
    __shared__ __align__(16) bf16_t As[128 * 32];
    __shared__ __align__(16) bf16_t Bs[128 * 32];

    int tid = threadIdx.x;
    int lane = tid & 63;
    int wave = tid >> 6;
    int m0 = blockIdx.x * 128;
    int n0 = blockIdx.y * 128;
    int wm = (wave & 1) * 64;
    int wn = (wave >> 1) * 64;
    int col = lane & 15;
    int g = lane >> 4;

    floatx4 acc[4][4] = {};

    int srow = wave * 32 + (lane >> 2);
    int scol = (lane & 3) * 8;
    const bf16_t* Ag = A + (size_t)(m0 + srow) * K + scol;
    const bf16_t* Bg = B + (size_t)(n0 + srow) * K + scol;
    bf16_t* AsW0 = &As[(wave * 2 + 0) * 512];
    bf16_t* AsW1 = &As[(wave * 2 + 1) * 512];
    bf16_t* BsW0 = &Bs[(wave * 2 + 0) * 512];
    bf16_t* BsW1 = &Bs[(wave * 2 + 1) * 512];
    size_t r16 = (size_t)16 * K;

    for (int kk = K >> 5; kk > 0; --kk) {
        __syncthreads();
        gload16(Ag, AsW0);
        gload16(Ag + r16, AsW1);
        gload16(Bg, BsW0);
        gload16(Bg + r16, BsW1);
        Ag += 32; Bg += 32;
        __syncthreads();

        bf16x8 af[4], bfr[4];
#pragma unroll
        for (int i = 0; i < 4; ++i) af[i] = *(const bf16x8*)(&As[(wm + i * 16 + col) * 32 + g * 8]);
#pragma unroll
        for (int j = 0; j < 4; ++j) bfr[j] = *(const bf16x8*)(&Bs[(wn + j * 16 + col) * 32 + g * 8]);
#pragma unroll
        for (int i = 0; i < 4; ++i)
#pragma unroll
            for (int j = 0; j < 4; ++j)
                acc[i][j] = MFMA16(af[i], bfr[j], acc[i][j]);
    }

#pragma unroll
    for (int i = 0; i < 4; ++i)
#pragma unroll
        for (int j = 0; j < 4; ++j) {
            int mrow = m0 + wm + i * 16 + g * 4;
            int ncol = n0 + wn + j * 16 + col;
            int h = ncol >> 8;
            int within = ncol & 255;
            if (within < 128) {
#pragma unroll
                for (int r = 0; r < 4; ++r)
                    kn[(size_t)(mrow + r) * 2048 + h * 128 + within] = (bf16_t)acc[i][j][r];
            } else {
                int d = within - 128;
                int bb = mrow >> 11;
                int s = mrow & 2047;
                bf16x4 pk;
#pragma unroll
                for (int r = 0; r < 4; ++r) pk[r] = (bf16_t)acc[i][j][r];
                *(bf16x4*)(vT + ((size_t)(bb * 16 + h) * 128 + d) * 2048 + s) = pk;
            }
        }
}

// ---------------------------------------------------------------------------
// RMSNorm
// ---------------------------------------------------------------------------
__global__ __launch_bounds__(256) void rmsnorm_kernel(const bf16_t* __restrict__ in, int in_stride,
                                                      const bf16_t* __restrict__ w,
                                                      bf16_t* __restrict__ out, int out_stride,
                                                      int C) {
    int row = blockIdx.x;
    int tid = threadIdx.x;
    const bf16_t* x = in + (size_t)row * in_stride;
    bool act = tid * 8 < C;
    float xs[8];
    float ss = 0.f;
    if (act) {
        bf16x8 v = *(const bf16x8*)(x + tid * 8);
#pragma unroll
        for (int j = 0; j < 8; ++j) {
            xs[j] = (float)v[j];
            ss += xs[j] * xs[j];
        }
    }
    for (int o = 32; o; o >>= 1) ss += __shfl_xor(ss, o, 64);
    __shared__ float red[4];
    if ((tid & 63) == 0) red[tid >> 6] = ss;
    __syncthreads();
    float tot = red[0] + red[1] + red[2] + red[3];
    float scale = rsqrtf(tot / (float)C + 1e-6f);
    if (act) {
        bf16x8 wv = *(const bf16x8*)(w + tid * 8);
        bf16x8 ov;
#pragma unroll
        for (int j = 0; j < 8; ++j) ov[j] = (bf16_t)((float)wv[j] * xs[j] * scale);
        *(bf16x8*)(out + (size_t)row * out_stride + tid * 8) = ov;
    }
}

// ---------------------------------------------------------------------------
// YaRN rope, in place (q_pe of 16 heads + k_pe in ckv).
// ---------------------------------------------------------------------------
__global__ __launch_bounds__(256) void rope_kernel(bf16_t* __restrict__ q,
                                                   bf16_t* __restrict__ ckv,
                                                   const int* __restrict__ pos_ids) {
    int tid = threadIdx.x;
    int lane = tid & 63;
    int gwave = (blockIdx.x * 256 + tid) >> 6;
    int unit = gwave * 2 + ((lane >> 5) & 1);
    int j = lane & 31;
    if (unit >= 4096 * 17) return;
    int t = unit / 17;
    int head = unit % 17;

    float fe = __expf(-(float)j * 0.28782313662425575f);
    float fi = fe * 0.025f;
    float ramp = fminf(fmaxf(((float)j - 10.0f) / 13.0f, 0.0f), 1.0f);
    float invf = fi * ramp + fe * (1.0f - ramp);
    float th = (float)pos_ids[t] * invf;
    float c = cosf(th);
    float s = sinf(th);

    bf16_t* base = (head < 16) ? (q + (size_t)t * 3072 + head * 192 + 128)
                               : (ckv + (size_t)t * 640 + 512);
    float e = (float)base[2 * j];
    float o = (float)base[2 * j + 1];
    base[j] = (bf16_t)(e * c - o * s);
    base[j + 32] = (bf16_t)(o * c + e * s);
}

// ---------------------------------------------------------------------------
// Causal flash attention v4: barrier-free, per-wave independent.
// S^T = K x Q (MFMA A=K, B=Q) -> each lane holds 16 keys of ONE query.
// K and V fragments read DIRECTLY from global (L2/LLC-resident; LDS staging
// had zero reuse -> pure transit overhead + 2 barriers/iter + 2-block LDS cap).
// P exchange via per-wave XOR-swizzled LDS buffer (lgkmcnt only, no barrier).
// Block: 128 q x (b,h); 4 independent waves x 32 q; k-tile 64.
// Softmax scale pre-folded into wq_b.
// ---------------------------------------------------------------------------
__global__ __launch_bounds__(256, 3) void attn_kernel(const bf16_t* __restrict__ q,
                                                      const bf16_t* __restrict__ kn,
                                                      const bf16_t* __restrict__ ckv,
                                                      const bf16_t* __restrict__ vT,
                                                      bf16_t* __restrict__ outp) {
    // per-wave P: 32 q x 64 k, XOR-swizzled (byte ^= (row&7)<<4) -> conflict-free
    __shared__ __align__(16) bf16_t Ps[4][32][64];

    int tid = threadIdx.x;
    int lane = tid & 63;
    int wave = tid >> 6;
    int x = blockIdx.x, y = blockIdx.y;
    // balance hedge: complementary cost under depth-first AND breadth-first dispatch
    int qt0 = x >> 1;
    int qt = (x & 1) ? (15 - qt0) : qt0;
    if (y >= 16) qt = 15 - qt;
    int b = y >> 4;
    int h = y & 15;
    int q0 = qt * 128;
    size_t tok0 = (size_t)b * 2048;
    int col = lane & 15;
    int g = lane >> 4;

    // Q fragments (B operand): q index = wave*32 + i*16 + col
    bf16x8 qf[2][6];
    {
        const bf16_t* qb = q + (tok0 + q0 + wave * 32 + col) * 3072 + h * 192 + g * 8;
#pragma unroll
        for (int i = 0; i < 2; ++i)
#pragma unroll
            for (int ks = 0; ks < 6; ++ks)
                qf[i][ks] = *(const bf16x8*)(qb + (size_t)i * 16 * 3072 + ks * 32);
    }

    float m_i[2] = {NEG_BIG, NEG_BIG};
    float l_i[2] = {0.f, 0.f};
    floatx4 o_acc[8][2] = {};            // [d m-tile][q n-tile]; col=q, row=d

    // per-lane loop-invariant bases (row term col*stride + col-group g*8 folded in)
    const bf16_t* knb = kn + tok0 * 2048 + (size_t)h * 128 + (size_t)col * 2048 + g * 8;
    const bf16_t* kpb = ckv + tok0 * 640 + 512 + (size_t)col * 640 + g * 8;
    const bf16_t* vb  = vT + (size_t)y * 128 * 2048 + (size_t)col * 2048 + g * 8;
    char* PsW = (char*)&Ps[wave][0][0];

    int niter = (q0 + 128) >> 6;
    for (int kt = 0; kt < niter; ++kt) {
        int k0 = kt * 64;

        // --- S^T: A = K (m=key, 4 tiles) direct from global, B = Q (n=q, 2 tiles)
        floatx4 s_acc[4][2] = {};
#pragma unroll
        for (int ks = 0; ks < 6; ++ks) {
            bf16x8 ak[4];
#pragma unroll
            for (int mt = 0; mt < 4; ++mt)
                ak[mt] = (ks < 4)
                    ? *(const bf16x8*)(knb + (size_t)(k0 + mt * 16) * 2048 + ks * 32)
                    : *(const bf16x8*)(kpb + (size_t)(k0 + mt * 16) * 640 + (ks - 4) * 32);
            __builtin_amdgcn_s_setprio(1);
#pragma unroll
            for (int mt = 0; mt < 4; ++mt)
#pragma unroll
                for (int i = 0; i < 2; ++i)
                    s_acc[mt][i] = MFMA16(ak[mt], qf[i][ks], s_acc[mt][i]);
            __builtin_amdgcn_s_setprio(0);
        }

        // online softmax: per lane, 16 keys of query (wave*32 + i*16 + col)
#pragma unroll
        for (int i = 0; i < 2; ++i) {
            int qg = q0 + wave * 32 + i * 16 + col;
            float mx = NEG_BIG;
#pragma unroll
            for (int mt = 0; mt < 4; ++mt)
#pragma unroll
                for (int r = 0; r < 4; ++r) {
                    int key = k0 + mt * 16 + g * 4 + r;
                    float s = (key <= qg) ? s_acc[mt][i][r] : NEG_BIG;
                    s_acc[mt][i][r] = s;
                    mx = fmaxf(mx, s);
                }
            mx = fmaxf(mx, __shfl_xor(mx, 16, 64));
            mx = fmaxf(mx, __shfl_xor(mx, 32, 64));
            float mnew = fmaxf(m_i[i], mx);
            float rs = 0.f;
            int row = i * 16 + col;
#pragma unroll
            for (int mt = 0; mt < 4; ++mt) {
                bf16x4 pk;
#pragma unroll
                for (int r = 0; r < 4; ++r) {
                    float p = __expf(s_acc[mt][i][r] - mnew);
                    rs += p;
                    pk[r] = (bf16_t)p;
                }
                int boff = (row * 128 + mt * 32 + g * 8) ^ ((row & 7) << 4);
                *(bf16x4*)(PsW + boff) = pk;
            }
            rs += __shfl_xor(rs, 16, 64);
            rs += __shfl_xor(rs, 32, 64);
            float alpha = __expf(m_i[i] - mnew);
            l_i[i] = l_i[i] * alpha + rs;
            m_i[i] = mnew;
#pragma unroll
            for (int mt = 0; mt < 8; ++mt)
#pragma unroll
                for (int r = 0; r < 4; ++r)
                    o_acc[mt][i][r] *= alpha;
        }

        // Ps is per-wave: only need this wave's LDS writes drained, no barrier
        asm volatile("s_waitcnt lgkmcnt(0)" ::: "memory");
        __builtin_amdgcn_sched_barrier(0);

        // --- O^T += V^T (A: m=d, 8 tiles, direct from global) x P (B: n=q, 2 tiles)
        bf16x8 bp[2][2];
#pragma unroll
        for (int kc = 0; kc < 2; ++kc)
#pragma unroll
            for (int i = 0; i < 2; ++i) {
                int row = i * 16 + col;
                int boff = (row * 128 + kc * 64 + g * 16) ^ ((row & 7) << 4);
                bp[kc][i] = *(const bf16x8*)(PsW + boff);
            }
#pragma unroll
        for (int mt = 0; mt < 8; ++mt) {
            bf16x8 av0 = *(const bf16x8*)(vb + (size_t)(mt * 16) * 2048 + k0);
            bf16x8 av1 = *(const bf16x8*)(vb + (size_t)(mt * 16) * 2048 + k0 + 32);
            __builtin_amdgcn_s_setprio(1);
#pragma unroll
            for (int i = 0; i < 2; ++i)
                o_acc[mt][i] = MFMA16(av0, bp[0][i], o_acc[mt][i]);
#pragma unroll
            for (int i = 0; i < 2; ++i)
                o_acc[mt][i] = MFMA16(av1, bp[1][i], o_acc[mt][i]);
            __builtin_amdgcn_s_setprio(0);
        }
    }

    // epilogue: lane holds d = mt*16 + g*4 + r (4 consecutive) for query col
#pragma unroll
    for (int i = 0; i < 2; ++i) {
        float inv = 1.0f / l_i[i];
        size_t trow = tok0 + q0 + wave * 32 + i * 16 + col;
        bf16_t* op = outp + trow * 2048 + h * 128;
#pragma unroll
        for (int mt = 0; mt < 8; ++mt) {
            bf16x4 pk;
#pragma unroll
            for (int r = 0; r < 4; ++r) pk[r] = (bf16_t)(o_acc[mt][i][r] * inv);
            *(bf16x4*)(op + mt * 16 + g * 4) = pk;
        }
    }
}

// ---------------------------------------------------------------------------
// Launch
// ---------------------------------------------------------------------------
extern "C" void kernel_launch(void* const* d_in, const int* in_sizes, int n_in,
                              void* d_out, int out_size, void* d_ws, size_t ws_size,
                              hipStream_t stream) {
    const void* hidden_raw = d_in[0];
    const int* pos = (const int*)d_in[1];
    const void* wq_a_raw = d_in[2];
    const void* q_ln_raw = d_in[3];
    const void* wq_b_raw = d_in[4];
    const void* wkv_a_raw = d_in[5];
    const void* kv_ln_raw = d_in[6];
    const void* wkv_b_raw = d_in[7];
    const void* wo_raw = d_in[8];

    char* ws = (char*)d_ws;
    int* flag = (int*)ws;          ws += 256;
    bf16_t* wkv_pad = (bf16_t*)ws; ws += (size_t)640 * 2048 * 2;
    bf16_t* q_a     = (bf16_t*)ws; ws += (size_t)4096 * 1536 * 2;
    bf16_t* qbuf    = (bf16_t*)ws; ws += (size_t)4096 * 3072 * 2;
    bf16_t* ckv     = (bf16_t*)ws; ws += (size_t)4096 * 640 * 2;
    bf16_t* kv_n    = (bf16_t*)ws; ws += (size_t)4096 * 512 * 2;
    bf16_t* knbuf   = (bf16_t*)ws; ws += (size_t)4096 * 2048 * 2;
    bf16_t* vTbuf   = (bf16_t*)ws; ws += (size_t)4096 * 2048 * 2;
    bf16_t* attno   = (bf16_t*)ws; ws += (size_t)4096 * 2048 * 2;
    bf16_t* outbf   = (bf16_t*)ws; ws += (size_t)4096 * 2048 * 2;
    bf16_t* hb      = (bf16_t*)ws; ws += (size_t)4096 * 2048 * 2;
    bf16_t* wqab    = (bf16_t*)ws; ws += (size_t)1536 * 2048 * 2;
    bf16_t* wqbb    = (bf16_t*)ws; ws += (size_t)3072 * 1536 * 2;
    bf16_t* wkvbb   = (bf16_t*)ws; ws += (size_t)4096 * 512 * 2;
    bf16_t* wob     = (bf16_t*)ws; ws += (size_t)2048 * 2048 * 2;
    bf16_t* qlnb    = (bf16_t*)ws; ws += 4096;
    bf16_t* kvlnb   = (bf16_t*)ws; ws += 4096;

    detect_kernel<<<1, 64, 0, stream>>>((const unsigned int*)q_ln_raw, flag);

    // softmax scale folded into wq_b (rope is linear, k_pe unscaled)
    double m = 0.1 * log(40.0) + 1.0;
    float scale = (float)((m * m) / sqrt(192.0));

    conv_in_kernel<<<4096, 256, 0, stream>>>(hidden_raw, hb, (long)4096 * 2048 / 8, flag);
    conv_in_kernel<<<1536, 256, 0, stream>>>(wq_a_raw, wqab, (long)1536 * 2048 / 8, flag);
    conv_in_kernel<<<1, 256, 0, stream>>>(q_ln_raw, qlnb, 1536 / 8, flag);
    conv_in_scale_kernel<<<2304, 256, 0, stream>>>(wq_b_raw, wqbb, (long)3072 * 1536 / 8, flag, scale);
    conv_in_kernel<<<1, 256, 0, stream>>>(kv_ln_raw, kvlnb, 512 / 8, flag);
    conv_in_kernel<<<1024, 256, 0, stream>>>(wkv_b_raw, wkvbb, (long)4096 * 512 / 8, flag);
    conv_in_kernel<<<2048, 256, 0, stream>>>(wo_raw, wob, (long)2048 * 2048 / 8, flag);
    pad_wkv_kernel<<<640, 256, 0, stream>>>(wkv_a_raw, wkv_pad, flag);

    // q_a = hidden @ wq_a^T           (4096 x 1536, K=2048)
    gemm_bf16<<<dim3(32, 12), 256, 0, stream>>>(hb, wqab, q_a, 4096, 1536, 2048);
    // ckv = hidden @ wkv_a_pad^T      (4096 x 640, K=2048)
    gemm_bf16<<<dim3(32, 5), 256, 0, stream>>>(hb, wkv_pad, ckv, 4096, 640, 2048);

    rmsnorm_kernel<<<4096, 256, 0, stream>>>(q_a, 1536, qlnb, q_a, 1536, 1536);
    rmsnorm_kernel<<<4096, 256, 0, stream>>>(ckv, 640, kvlnb, kv_n, 512, 512);

    // q = q_n @ (scale*wq_b)^T        (4096 x 3072, K=1536)
    gemm_bf16<<<dim3(32, 24), 256, 0, stream>>>(q_a, wqbb, qbuf, 4096, 3072, 1536);
    // kv = kv_n @ wkv_b^T, split epilogue (k_nope -> knbuf, v -> vT)
    gemm_kv<<<dim3(32, 32), 256, 0, stream>>>(kv_n, wkvbb, knbuf, vTbuf, 512);

    // rope on q_pe (16 heads) and k_pe (ckv cols 512..575)
    rope_kernel<<<8704, 256, 0, stream>>>(qbuf, ckv, pos);

    attn_kernel<<<dim3(16, 32), 256, 0, stream>>>(qbuf, knbuf, ckv, vTbuf, attno);

    // out = attno @ wo^T              (4096 x 2048, K=2048)
    gemm_bf16<<<dim3(32, 16), 256, 0, stream>>>(attno, wob, outbf, 4096, 2048, 2048);

    conv_out_kernel<<<4096, 256, 0, stream>>>(outbf, d_out, (long)4096 * 2048 / 8, flag);
}

// Round 2
// 574.319 us; speedup vs baseline: 1.1939x; 1.1939x over previous
//
#include <hip/hip_runtime.h>
#include <hip/hip_bf16.h>
#include <math.h>

typedef __bf16 bf16_t;
typedef __bf16 bf16x4 __attribute__((ext_vector_type(4)));
typedef __bf16 bf16x8 __attribute__((ext_vector_type(8)));
typedef float floatx4 __attribute__((ext_vector_type(4)));

#define MFMA16(a, b, c) __builtin_amdgcn_mfma_f32_16x16x32_bf16((a), (b), (c), 0, 0, 0)

#define NEG_BIG (-1e30f)

// async global->LDS, 16B per lane; lds dest = wave-uniform base + lane*16
__device__ __forceinline__ void gload16(const bf16_t* g, bf16_t* l) {
    __builtin_amdgcn_global_load_lds(
        (const __attribute__((address_space(1))) unsigned int*)g,
        (__attribute__((address_space(3))) unsigned int*)l,
        16, 0, 0);
}

// ---------------------------------------------------------------------------
// Detect input dtype: q_a_ln_w is all ones. fp32 word0 = 0x3F800000,
// bf16-packed word0 = 0x3F803F80. flag=1 -> bf16, flag=0 -> fp32.
// ---------------------------------------------------------------------------
__global__ void detect_kernel(const unsigned int* __restrict__ lnw, int* __restrict__ flag) {
    if (threadIdx.x == 0 && blockIdx.x == 0)
        flag[0] = (lnw[0] == 0x3F803F80u) ? 1 : 0;
}

__global__ __launch_bounds__(256) void conv_in_kernel(const void* __restrict__ src,
                                                      bf16_t* __restrict__ dst,
                                                      long nchunk,
                                                      const int* __restrict__ flag) {
    long i = (long)blockIdx.x * 256 + threadIdx.x;
    if (i >= nchunk) return;
    if (flag[0]) {
        ((uint4*)dst)[i] = ((const uint4*)src)[i];
    } else {
        const float* f = (const float*)src + i * 8;
        bf16x8 o;
#pragma unroll
        for (int j = 0; j < 8; ++j) o[j] = (bf16_t)f[j];
        ((bf16x8*)dst)[i] = o;
    }
}

// conv with scalar multiply (used to fold softmax scale into wq_b)
__global__ __launch_bounds__(256) void conv_in_scale_kernel(const void* __restrict__ src,
                                                            bf16_t* __restrict__ dst,
                                                            long nchunk,
                                                            const int* __restrict__ flag,
                                                            float s) {
    long i = (long)blockIdx.x * 256 + threadIdx.x;
    if (i >= nchunk) return;
    bf16x8 o;
    if (flag[0]) {
        bf16x8 v = ((const bf16x8*)src)[i];
#pragma unroll
        for (int j = 0; j < 8; ++j) o[j] = (bf16_t)((float)v[j] * s);
    } else {
        const float* f = (const float*)src + i * 8;
#pragma unroll
        for (int j = 0; j < 8; ++j) o[j] = (bf16_t)(f[j] * s);
    }
    ((bf16x8*)dst)[i] = o;
}

__global__ __launch_bounds__(256) void conv_out_kernel(const bf16_t* __restrict__ src,
                                                       void* __restrict__ dst,
                                                       long nchunk,
                                                       const int* __restrict__ flag) {
    long i = (long)blockIdx.x * 256 + threadIdx.x;
    if (i >= nchunk) return;
    bf16x8 v = ((const bf16x8*)src)[i];
    if (flag[0]) {
        ((uint4*)dst)[i] = *(const uint4*)&v;
    } else {
        float* f = (float*)dst + i * 8;
#pragma unroll
        for (int j = 0; j < 8; ++j) f[j] = (float)v[j];
    }
}

__global__ __launch_bounds__(256) void pad_wkv_kernel(const void* __restrict__ src,
                                                      bf16_t* __restrict__ dst,
                                                      const int* __restrict__ flag) {
    long idx = (long)blockIdx.x * 256 + threadIdx.x;
    long e0 = idx * 8;
    if (e0 >= (long)640 * 2048) return;
    int row = (int)(e0 >> 11);
    bf16x8 v;
#pragma unroll
    for (int j = 0; j < 8; ++j) v[j] = (bf16_t)0.0f;
    if (row < 576) {
        if (flag[0]) {
            v = *(const bf16x8*)((const bf16_t*)src + e0);
        } else {
            const float* f = (const float*)src + e0;
#pragma unroll
            for (int j = 0; j < 8; ++j) v[j] = (bf16_t)f[j];
        }
    }
    *(bf16x8*)(dst + e0) = v;
}

// ---------------------------------------------------------------------------
// GEMM (m97 structure): C[M,N] = A[M,K] @ B[N,K]^T, bf16, fp32 acc.
// 128x128 tile, BK=32, async global_load_lds width-16 staging, unpadded LDS.
// ---------------------------------------------------------------------------
__global__ __launch_bounds__(256) void gemm_bf16(const bf16_t* __restrict__ A,
                                                 const bf16_t* __restrict__ B,
                                                 bf16_t* __restrict__ C,
                                                 int M, int N, int K) {
    __shared__ __align__(16) bf16_t As[128 * 32];
    __shared__ __align__(16) bf16_t Bs[128 * 32];

    int tid = threadIdx.x;
    int lane = tid & 63;
    int wave = tid >> 6;
    int m0 = blockIdx.x * 128;
    int n0 = blockIdx.y * 128;
    int wm = (wave & 1) * 64;
    int wn = (wave >> 1) * 64;
    int col = lane & 15;
    int g = lane >> 4;

    floatx4 acc[4][4] = {};

    // staging: wave w covers rows [w*32, w*32+32) via two 16-row async calls
    int srow = wave * 32 + (lane >> 2);
    int scol = (lane & 3) * 8;
    const bf16_t* Ag = A + (size_t)(m0 + srow) * K + scol;
    const bf16_t* Bg = B + (size_t)(n0 + srow) * K + scol;
    bf16_t* AsW0 = &As[(wave * 2 + 0) * 512];
    bf16_t* AsW1 = &As[(wave * 2 + 1) * 512];
    bf16_t* BsW0 = &Bs[(wave * 2 + 0) * 512];
    bf16_t* BsW1 = &Bs[(wave * 2 + 1) * 512];
    size_t r16 = (size_t)16 * K;

    for (int kk = K >> 5; kk > 0; --kk) {
        __syncthreads();
        gload16(Ag, AsW0);
        gload16(Ag + r16, AsW1);
        gload16(Bg, BsW0);
        gload16(Bg + r16, BsW1);
        Ag += 32; Bg += 32;
        __syncthreads();

        bf16x8 af[4], bfr[4];
#pragma unroll
        for (int i = 0; i < 4; ++i) af[i] = *(const bf16x8*)(&As[(wm + i * 16 + col) * 32 + g * 8]);
#pragma unroll
        for (int j = 0; j < 4; ++j) bfr[j] = *(const bf16x8*)(&Bs[(wn + j * 16 + col) * 32 + g * 8]);
#pragma unroll
        for (int i = 0; i < 4; ++i)
#pragma unroll
            for (int j = 0; j < 4; ++j)
                acc[i][j] = MFMA16(af[i], bfr[j], acc[i][j]);
    }

#pragma unroll
    for (int i = 0; i < 4; ++i)
#pragma unroll
        for (int j = 0; j < 4; ++j) {
            size_t mrow = (size_t)(m0 + wm + i * 16 + g * 4);
            size_t ncol = (size_t)(n0 + wn + j * 16 + col);
            bf16_t* cp = C + mrow * N + ncol;
#pragma unroll
            for (int r = 0; r < 4; ++r) cp[(size_t)r * N] = (bf16_t)acc[i][j][r];
        }
}

// ---------------------------------------------------------------------------
// kv GEMM (m97 staging) with split epilogue:
//   k_nope -> kn[tok][16*128],  v -> vT[b][h][128 d][2048 s]
// ---------------------------------------------------------------------------
__global__ __launch_bounds__(256) void gemm_kv(const bf16_t* __restrict__ A,
                                               const bf16_t* __restrict__ B,
                                               bf16_t* __restrict__ kn,
                                               bf16_t* __restrict__ vT,
                                               int K) {
    __shared__ __align__(16) bf16_t As[128 * 32];
    __shared__ __align__(16) bf16_t Bs[128 * 32];

    int tid = threadIdx.x;
    int lane = tid & 63;
    int wave = tid >> 6;
    int m0 = blockIdx.x * 128;
    int n0 = blockIdx.y * 128;
    int wm = (wave & 1) * 64;
    int wn = (wave >> 1) * 64;
    int col = lane & 15;
    int g = lane >> 4;

    floatx4 acc[4][4] = {};

    int srow = wave * 32 + (lane >> 2);
    int scol = (lane & 3) * 8;
    const bf16_t* Ag = A + (size_t)(m0 + srow) * K + scol;
    const bf16_t* Bg = B + (size_t)(n0 + srow) * K + scol;
    bf16_t* AsW0 = &As[(wave * 2 + 0) * 512];
    bf16_t* AsW1 = &As[(wave * 2 + 1) * 512];
    bf16_t* BsW0 = &Bs[(wave * 2 + 0) * 512];
    bf16_t* BsW1 = &Bs[(wave * 2 + 1) * 512];
    size_t r16 = (size_t)16 * K;

    for (int kk = K >> 5; kk > 0; --kk) {
        __syncthreads();
        gload16(Ag, AsW0);
        gload16(Ag + r16, AsW1);
        gload16(Bg, BsW0);
        gload16(Bg + r16, BsW1);
        Ag += 32; Bg += 32;
        __syncthreads();

        bf16x8 af[4], bfr[4];
#pragma unroll
        for (int i = 0; i < 4; ++i) af[i] = *(const bf16x8*)(&As[(wm + i * 16 + col) * 32 + g * 8]);
#pragma unroll
        for (int j = 0; j < 4; ++j) bfr[j] = *(const bf16x8*)(&Bs[(wn + j * 16 + col) * 32 + g * 8]);
#pragma unroll
        for (int i = 0; i < 4; ++i)
#pragma unroll
            for (int j = 0; j < 4; ++j)
                acc[i][j] = MFMA16(af[i], bfr[j], acc[i][j]);
    }

#pragma unroll
    for (int i = 0; i < 4; ++i)
#pragma unroll
        for (int j = 0; j < 4; ++j) {
            int mrow = m0 + wm + i * 16 + g * 4;
            int ncol = n0 + wn + j * 16 + col;
            int h = ncol >> 8;
            int within = ncol & 255;
            if (within < 128) {
#pragma unroll
                for (int r = 0; r < 4; ++r)
                    kn[(size_t)(mrow + r) * 2048 + h * 128 + within] = (bf16_t)acc[i][j][r];
            } else {
                int d = within - 128;
                int bb = mrow >> 11;
                int s = mrow & 2047;
                bf16x4 pk;
#pragma unroll
                for (int r = 0; r < 4; ++r) pk[r] = (bf16_t)acc[i][j][r];
                *(bf16x4*)(vT + ((size_t)(bb * 16 + h) * 128 + d) * 2048 + s) = pk;
            }
        }
}

// ---------------------------------------------------------------------------
// RMSNorm
// ---------------------------------------------------------------------------
__global__ __launch_bounds__(256) void rmsnorm_kernel(const bf16_t* __restrict__ in, int in_stride,
                                                      const bf16_t* __restrict__ w,
                                                      bf16_t* __restrict__ out, int out_stride,
                                                      int C) {
    int row = blockIdx.x;
    int tid = threadIdx.x;
    const bf16_t* x = in + (size_t)row * in_stride;
    bool act = tid * 8 < C;
    float xs[8];
    float ss = 0.f;
    if (act) {
        bf16x8 v = *(const bf16x8*)(x + tid * 8);
#pragma unroll
        for (int j = 0; j < 8; ++j) {
            xs[j] = (float)v[j];
            ss += xs[j] * xs[j];
        }
    }
    for (int o = 32; o; o >>= 1) ss += __shfl_xor(ss, o, 64);
    __shared__ float red[4];
    if ((tid & 63) == 0) red[tid >> 6] = ss;
    __syncthreads();
    float tot = red[0] + red[1] + red[2] + red[3];
    float scale = rsqrtf(tot / (float)C + 1e-6f);
    if (act) {
        bf16x8 wv = *(const bf16x8*)(w + tid * 8);
        bf16x8 ov;
#pragma unroll
        for (int j = 0; j < 8; ++j) ov[j] = (bf16_t)((float)wv[j] * xs[j] * scale);
        *(bf16x8*)(out + (size_t)row * out_stride + tid * 8) = ov;
    }
}

// ---------------------------------------------------------------------------
// YaRN rope, in place (q_pe of 16 heads + k_pe in ckv).
// ---------------------------------------------------------------------------
__global__ __launch_bounds__(256) void rope_kernel(bf16_t* __restrict__ q,
                                                   bf16_t* __restrict__ ckv,
                                                   const int* __restrict__ pos_ids) {
    int tid = threadIdx.x;
    int lane = tid & 63;
    int gwave = (blockIdx.x * 256 + tid) >> 6;
    int unit = gwave * 2 + ((lane >> 5) & 1);
    int j = lane & 31;
    if (unit >= 4096 * 17) return;
    int t = unit / 17;
    int head = unit % 17;

    float fe = __expf(-(float)j * 0.28782313662425575f);
    float fi = fe * 0.025f;
    float ramp = fminf(fmaxf(((float)j - 10.0f) / 13.0f, 0.0f), 1.0f);
    float invf = fi * ramp + fe * (1.0f - ramp);
    float th = (float)pos_ids[t] * invf;
    float c = cosf(th);
    float s = sinf(th);

    bf16_t* base = (head < 16) ? (q + (size_t)t * 3072 + head * 192 + 128)
                               : (ckv + (size_t)t * 640 + 512);
    float e = (float)base[2 * j];
    float o = (float)base[2 * j + 1];
    base[j] = (bf16_t)(e * c - o * s);
    base[j + 32] = (bf16_t)(o * c + e * s);
}

// ---------------------------------------------------------------------------
// Causal flash attention v5: LDS-staged (4x wave reuse) + XOR-swizzled tiles
// (conflict-free ds_read_b128) + 1-tile register prefetch (T14: global loads
// issued right after stage barrier, consumed next iteration -> latency hidden
// under a full tile of compute). Per-wave Ps sync via lgkmcnt only.
// Block: 128 q x (b,h); 4 waves x 32 q; k-tile 64. Scale pre-folded in wq_b.
// ---------------------------------------------------------------------------
__global__ __launch_bounds__(256, 2) void attn_kernel(const bf16_t* __restrict__ q,
                                                      const bf16_t* __restrict__ kn,
                                                      const bf16_t* __restrict__ ckv,
                                                      const bf16_t* __restrict__ vT,
                                                      bf16_t* __restrict__ outp) {
    // all tiles XOR-swizzled: 16B chunk index ^= (row & 7)
    __shared__ __align__(16) bf16_t Ks[64][192];    // 64 keys x 192 d
    __shared__ __align__(16) bf16_t Vt[128][64];    // 128 d x 64 keys
    __shared__ __align__(16) bf16_t Ps[4][32][64];  // per-wave P: 32 q x 64 k

    int tid = threadIdx.x;
    int lane = tid & 63;
    int wave = tid >> 6;
    int x = blockIdx.x, y = blockIdx.y;
    // balance hedge: complementary cost under depth-first AND breadth-first dispatch
    int qt0 = x >> 1;
    int qt = (x & 1) ? (15 - qt0) : qt0;
    if (y >= 16) qt = 15 - qt;
    int b = y >> 4;
    int h = y & 15;
    int q0 = qt * 128;
    size_t tok0 = (size_t)b * 2048;
    int col = lane & 15;
    int g = lane >> 4;

    // Q fragments (B operand): q index = wave*32 + i*16 + col
    bf16x8 qf[2][6];
    {
        const bf16_t* qb = q + (tok0 + q0 + wave * 32 + col) * 3072 + h * 192 + g * 8;
#pragma unroll
        for (int i = 0; i < 2; ++i)
#pragma unroll
            for (int ks = 0; ks < 6; ++ks)
                qf[i][ks] = *(const bf16x8*)(qb + (size_t)i * 16 * 3072 + ks * 32);
    }

    // staging geometry: K = 64 rows x 24 chunks of 16B; V = 128 rows x 8 chunks
    const bf16_t* kg[6]; int kstep[6]; bf16_t* kl[6];
#pragma unroll
    for (int i = 0; i < 6; ++i) {
        int c = tid + i * 256;
        int row = c / 24;
        int ch = c % 24;
        if (ch < 16) { kg[i] = kn + (tok0 + row) * 2048 + h * 128 + ch * 8; kstep[i] = 64 * 2048; }
        else         { kg[i] = ckv + (tok0 + row) * 640 + 512 + (ch - 16) * 8; kstep[i] = 64 * 640; }
        kl[i] = &Ks[row][(ch ^ (row & 7)) * 8];
    }
    const bf16_t* vg[4]; bf16_t* vl[4];
#pragma unroll
    for (int i = 0; i < 4; ++i) {
        int c = tid + i * 256;
        int d = c >> 3;
        int ch = c & 7;
        vg[i] = vT + ((size_t)y * 128 + d) * 2048 + ch * 8;
        vl[i] = &Vt[d][(ch ^ (d & 7)) * 8];
    }

    float m_i[2] = {NEG_BIG, NEG_BIG};
    float l_i[2] = {0.f, 0.f};
    floatx4 o_acc[8][2] = {};            // [d m-tile][q n-tile]; col=q, row=d

    char* PsW = (char*)&Ps[wave][0][0];
    int xsw = col & 7;                   // read-side swizzle key (rows mt*16+col)

    // prologue: prefetch tile 0 into registers
    uint4 kpre[6], vpre[4];
#pragma unroll
    for (int i = 0; i < 6; ++i) { kpre[i] = *(const uint4*)kg[i]; kg[i] += kstep[i]; }
#pragma unroll
    for (int i = 0; i < 4; ++i) { vpre[i] = *(const uint4*)vg[i]; vg[i] += 64; }

    int niter = (q0 + 128) >> 6;
    for (int kt = 0; kt < niter; ++kt) {
        int k0 = kt * 64;

        __syncthreads();   // all waves done reading previous tile
#pragma unroll
        for (int i = 0; i < 6; ++i) *(uint4*)kl[i] = kpre[i];
#pragma unroll
        for (int i = 0; i < 4; ++i) *(uint4*)vl[i] = vpre[i];
        __syncthreads();   // tile visible

        // prefetch next tile (hidden under this tile's compute)
        if (kt + 1 < niter) {
#pragma unroll
            for (int i = 0; i < 6; ++i) { kpre[i] = *(const uint4*)kg[i]; kg[i] += kstep[i]; }
#pragma unroll
            for (int i = 0; i < 4; ++i) { vpre[i] = *(const uint4*)vg[i]; vg[i] += 64; }
        }

        // --- S^T: A = K (m=key, 4 tiles), B = Q (n=q, 2 tiles)
        floatx4 s_acc[4][2] = {};
#pragma unroll
        for (int ks = 0; ks < 6; ++ks) {
            bf16x8 ak[4];
#pragma unroll
            for (int mt = 0; mt < 4; ++mt)
                ak[mt] = *(const bf16x8*)(&Ks[mt * 16 + col][((4 * ks + g) ^ xsw) * 8]);
            __builtin_amdgcn_s_setprio(1);
#pragma unroll
            for (int mt = 0; mt < 4; ++mt)
#pragma unroll
                for (int i = 0; i < 2; ++i)
                    s_acc[mt][i] = MFMA16(ak[mt], qf[i][ks], s_acc[mt][i]);
            __builtin_amdgcn_s_setprio(0);
        }

        // online softmax: per lane, 16 keys of query (wave*32 + i*16 + col)
#pragma unroll
        for (int i = 0; i < 2; ++i) {
            int qg = q0 + wave * 32 + i * 16 + col;
            float mx = NEG_BIG;
#pragma unroll
            for (int mt = 0; mt < 4; ++mt)
#pragma unroll
                for (int r = 0; r < 4; ++r) {
                    int key = k0 + mt * 16 + g * 4 + r;
                    float s = (key <= qg) ? s_acc[mt][i][r] : NEG_BIG;
                    s_acc[mt][i][r] = s;
                    mx = fmaxf(mx, s);
                }
            mx = fmaxf(mx, __shfl_xor(mx, 16, 64));
            mx = fmaxf(mx, __shfl_xor(mx, 32, 64));
            float mnew = fmaxf(m_i[i], mx);
            float rs = 0.f;
            int row = i * 16 + col;
#pragma unroll
            for (int mt = 0; mt < 4; ++mt) {
                bf16x4 pk;
#pragma unroll
                for (int r = 0; r < 4; ++r) {
                    float p = __expf(s_acc[mt][i][r] - mnew);
                    rs += p;
                    pk[r] = (bf16_t)p;
                }
                int boff = (row * 128 + mt * 32 + g * 8) ^ ((row & 7) << 4);
                *(bf16x4*)(PsW + boff) = pk;
            }
            rs += __shfl_xor(rs, 16, 64);
            rs += __shfl_xor(rs, 32, 64);
            float alpha = __expf(m_i[i] - mnew);
            l_i[i] = l_i[i] * alpha + rs;
            m_i[i] = mnew;
#pragma unroll
            for (int mt = 0; mt < 8; ++mt)
#pragma unroll
                for (int r = 0; r < 4; ++r)
                    o_acc[mt][i][r] *= alpha;
        }

        // Ps is per-wave: only this wave's LDS writes need draining, no barrier
        asm volatile("s_waitcnt lgkmcnt(0)" ::: "memory");
        __builtin_amdgcn_sched_barrier(0);

        // --- O^T += V^T (A: m=d, 8 tiles) x P (B: n=q, 2 tiles), 64-key contraction
#pragma unroll
        for (int kc = 0; kc < 2; ++kc) {
            bf16x8 bp[2];
#pragma unroll
            for (int i = 0; i < 2; ++i) {
                int row = i * 16 + col;
                int boff = (row * 128 + kc * 64 + g * 16) ^ ((row & 7) << 4);
                bp[i] = *(const bf16x8*)(PsW + boff);
            }
#pragma unroll
            for (int mt = 0; mt < 8; ++mt) {
                bf16x8 av = *(const bf16x8*)(&Vt[mt * 16 + col][((4 * kc + g) ^ xsw) * 8]);
                __builtin_amdgcn_s_setprio(1);
#pragma unroll
                for (int i = 0; i < 2; ++i)
                    o_acc[mt][i] = MFMA16(av, bp[i], o_acc[mt][i]);
                __builtin_amdgcn_s_setprio(0);
            }
        }
    }

    // epilogue: lane holds d = mt*16 + g*4 + r (4 consecutive) for query col
#pragma unroll
    for (int i = 0; i < 2; ++i) {
        float inv = 1.0f / l_i[i];
        size_t trow = tok0 + q0 + wave * 32 + i * 16 + col;
        bf16_t* op = outp + trow * 2048 + h * 128;
#pragma unroll
        for (int mt = 0; mt < 8; ++mt) {
            bf16x4 pk;
#pragma unroll
            for (int r = 0; r < 4; ++r) pk[r] = (bf16_t)(o_acc[mt][i][r] * inv);
            *(bf16x4*)(op + mt * 16 + g * 4) = pk;
        }
    }
}

// ---------------------------------------------------------------------------
// Launch
// ---------------------------------------------------------------------------
extern "C" void kernel_launch(void* const* d_in, const int* in_sizes, int n_in,
                              void* d_out, int out_size, void* d_ws, size_t ws_size,
                              hipStream_t stream) {
    const void* hidden_raw = d_in[0];
    const int* pos = (const int*)d_in[1];
    const void* wq_a_raw = d_in[2];
    const void* q_ln_raw = d_in[3];
    const void* wq_b_raw = d_in[4];
    const void* wkv_a_raw = d_in[5];
    const void* kv_ln_raw = d_in[6];
    const void* wkv_b_raw = d_in[7];
    const void* wo_raw = d_in[8];

    char* ws = (char*)d_ws;
    int* flag = (int*)ws;          ws += 256;
    bf16_t* wkv_pad = (bf16_t*)ws; ws += (size_t)640 * 2048 * 2;
    bf16_t* q_a     = (bf16_t*)ws; ws += (size_t)4096 * 1536 * 2;
    bf16_t* qbuf    = (bf16_t*)ws; ws += (size_t)4096 * 3072 * 2;
    bf16_t* ckv     = (bf16_t*)ws; ws += (size_t)4096 * 640 * 2;
    bf16_t* kv_n    = (bf16_t*)ws; ws += (size_t)4096 * 512 * 2;
    bf16_t* knbuf   = (bf16_t*)ws; ws += (size_t)4096 * 2048 * 2;
    bf16_t* vTbuf   = (bf16_t*)ws; ws += (size_t)4096 * 2048 * 2;
    bf16_t* attno   = (bf16_t*)ws; ws += (size_t)4096 * 2048 * 2;
    bf16_t* outbf   = (bf16_t*)ws; ws += (size_t)4096 * 2048 * 2;
    bf16_t* hb      = (bf16_t*)ws; ws += (size_t)4096 * 2048 * 2;
    bf16_t* wqab    = (bf16_t*)ws; ws += (size_t)1536 * 2048 * 2;
    bf16_t* wqbb    = (bf16_t*)ws; ws += (size_t)3072 * 1536 * 2;
    bf16_t* wkvbb   = (bf16_t*)ws; ws += (size_t)4096 * 512 * 2;
    bf16_t* wob     = (bf16_t*)ws; ws += (size_t)2048 * 2048 * 2;
    bf16_t* qlnb    = (bf16_t*)ws; ws += 4096;
    bf16_t* kvlnb   = (bf16_t*)ws; ws += 4096;

    detect_kernel<<<1, 64, 0, stream>>>((const unsigned int*)q_ln_raw, flag);

    // softmax scale folded into wq_b (rope is linear, k_pe unscaled)
    double m = 0.1 * log(40.0) + 1.0;
    float scale = (float)((m * m) / sqrt(192.0));

    conv_in_kernel<<<4096, 256, 0, stream>>>(hidden_raw, hb, (long)4096 * 2048 / 8, flag);
    conv_in_kernel<<<1536, 256, 0, stream>>>(wq_a_raw, wqab, (long)1536 * 2048 / 8, flag);
    conv_in_kernel<<<1, 256, 0, stream>>>(q_ln_raw, qlnb, 1536 / 8, flag);
    conv_in_scale_kernel<<<2304, 256, 0, stream>>>(wq_b_raw, wqbb, (long)3072 * 1536 / 8, flag, scale);
    conv_in_kernel<<<1, 256, 0, stream>>>(kv_ln_raw, kvlnb, 512 / 8, flag);
    conv_in_kernel<<<1024, 256, 0, stream>>>(wkv_b_raw, wkvbb, (long)4096 * 512 / 8, flag);
    conv_in_kernel<<<2048, 256, 0, stream>>>(wo_raw, wob, (long)2048 * 2048 / 8, flag);
    pad_wkv_kernel<<<640, 256, 0, stream>>>(wkv_a_raw, wkv_pad, flag);

    // q_a = hidden @ wq_a^T           (4096 x 1536, K=2048)
    gemm_bf16<<<dim3(32, 12), 256, 0, stream>>>(hb, wqab, q_a, 4096, 1536, 2048);
    // ckv = hidden @ wkv_a_pad^T      (4096 x 640, K=2048)
    gemm_bf16<<<dim3(32, 5), 256, 0, stream>>>(hb, wkv_pad, ckv, 4096, 640, 2048);

    rmsnorm_kernel<<<4096, 256, 0, stream>>>(q_a, 1536, qlnb, q_a, 1536, 1536);
    rmsnorm_kernel<<<4096, 256, 0, stream>>>(ckv, 640, kvlnb, kv_n, 512, 512);

    // q = q_n @ (scale*wq_b)^T        (4096 x 3072, K=1536)
    gemm_bf16<<<dim3(32, 24), 256, 0, stream>>>(q_a, wqbb, qbuf, 4096, 3072, 1536);
    // kv = kv_n @ wkv_b^T, split epilogue (k_nope -> knbuf, v -> vT)
    gemm_kv<<<dim3(32, 32), 256, 0, stream>>>(kv_n, wkvbb, knbuf, vTbuf, 512);

    // rope on q_pe (16 heads) and k_pe (ckv cols 512..575)
    rope_kernel<<<8704, 256, 0, stream>>>(qbuf, ckv, pos);

    attn_kernel<<<dim3(16, 32), 256, 0, stream>>>(qbuf, knbuf, ckv, vTbuf, attno);

    // out = attno @ wo^T              (4096 x 2048, K=2048)
    gemm_bf16<<<dim3(32, 16), 256, 0, stream>>>(attno, wob, outbf, 4096, 2048, 2048);

    conv_out_kernel<<<4096, 256, 0, stream>>>(outbf, d_out, (long)4096 * 2048 / 8, flag);
}

// Round 3
// 554.026 us; speedup vs baseline: 1.2377x; 1.0366x over previous
//
#include <hip/hip_runtime.h>
#include <hip/hip_bf16.h>
#include <math.h>

typedef __bf16 bf16_t;
typedef __bf16 bf16x4 __attribute__((ext_vector_type(4)));
typedef __bf16 bf16x8 __attribute__((ext_vector_type(8)));
typedef float floatx4 __attribute__((ext_vector_type(4)));

#define MFMA16(a, b, c) __builtin_amdgcn_mfma_f32_16x16x32_bf16((a), (b), (c), 0, 0, 0)

#define NEG_BIG (-1e30f)

// async global->LDS, 16B per lane; lds dest = wave-uniform base + lane*16
__device__ __forceinline__ void gload16(const bf16_t* g, bf16_t* l) {
    __builtin_amdgcn_global_load_lds(
        (const __attribute__((address_space(1))) unsigned int*)g,
        (__attribute__((address_space(3))) unsigned int*)l,
        16, 0, 0);
}

// ---------------------------------------------------------------------------
// Detect input dtype: q_a_ln_w is all ones. fp32 word0 = 0x3F800000,
// bf16-packed word0 = 0x3F803F80. flag=1 -> bf16, flag=0 -> fp32.
// ---------------------------------------------------------------------------
__global__ void detect_kernel(const unsigned int* __restrict__ lnw, int* __restrict__ flag) {
    if (threadIdx.x == 0 && blockIdx.x == 0)
        flag[0] = (lnw[0] == 0x3F803F80u) ? 1 : 0;
}

__global__ __launch_bounds__(256) void conv_in_kernel(const void* __restrict__ src,
                                                      bf16_t* __restrict__ dst,
                                                      long nchunk,
                                                      const int* __restrict__ flag) {
    long i = (long)blockIdx.x * 256 + threadIdx.x;
    if (i >= nchunk) return;
    if (flag[0]) {
        ((uint4*)dst)[i] = ((const uint4*)src)[i];
    } else {
        const float* f = (const float*)src + i * 8;
        bf16x8 o;
#pragma unroll
        for (int j = 0; j < 8; ++j) o[j] = (bf16_t)f[j];
        ((bf16x8*)dst)[i] = o;
    }
}

// conv with scalar multiply (used to fold softmax scale into wq_b)
__global__ __launch_bounds__(256) void conv_in_scale_kernel(const void* __restrict__ src,
                                                            bf16_t* __restrict__ dst,
                                                            long nchunk,
                                                            const int* __restrict__ flag,
                                                            float s) {
    long i = (long)blockIdx.x * 256 + threadIdx.x;
    if (i >= nchunk) return;
    bf16x8 o;
    if (flag[0]) {
        bf16x8 v = ((const bf16x8*)src)[i];
#pragma unroll
        for (int j = 0; j < 8; ++j) o[j] = (bf16_t)((float)v[j] * s);
    } else {
        const float* f = (const float*)src + i * 8;
#pragma unroll
        for (int j = 0; j < 8; ++j) o[j] = (bf16_t)(f[j] * s);
    }
    ((bf16x8*)dst)[i] = o;
}

__global__ __launch_bounds__(256) void conv_out_kernel(const bf16_t* __restrict__ src,
                                                       void* __restrict__ dst,
                                                       long nchunk,
                                                       const int* __restrict__ flag) {
    long i = (long)blockIdx.x * 256 + threadIdx.x;
    if (i >= nchunk) return;
    bf16x8 v = ((const bf16x8*)src)[i];
    if (flag[0]) {
        ((uint4*)dst)[i] = *(const uint4*)&v;
    } else {
        float* f = (float*)dst + i * 8;
#pragma unroll
        for (int j = 0; j < 8; ++j) f[j] = (float)v[j];
    }
}

__global__ __launch_bounds__(256) void pad_wkv_kernel(const void* __restrict__ src,
                                                      bf16_t* __restrict__ dst,
                                                      const int* __restrict__ flag) {
    long idx = (long)blockIdx.x * 256 + threadIdx.x;
    long e0 = idx * 8;
    if (e0 >= (long)640 * 2048) return;
    int row = (int)(e0 >> 11);
    bf16x8 v;
#pragma unroll
    for (int j = 0; j < 8; ++j) v[j] = (bf16_t)0.0f;
    if (row < 576) {
        if (flag[0]) {
            v = *(const bf16x8*)((const bf16_t*)src + e0);
        } else {
            const float* f = (const float*)src + e0;
#pragma unroll
            for (int j = 0; j < 8; ++j) v[j] = (bf16_t)f[j];
        }
    }
    *(bf16x8*)(dst + e0) = v;
}

// ---------------------------------------------------------------------------
// GEMM (m97 structure): C[M,N] = A[M,K] @ B[N,K]^T, bf16, fp32 acc.
// 128x128 tile, BK=32, async global_load_lds width-16 staging, unpadded LDS.
// ---------------------------------------------------------------------------
__global__ __launch_bounds__(256) void gemm_bf16(const bf16_t* __restrict__ A,
                                                 const bf16_t* __restrict__ B,
                                                 bf16_t* __restrict__ C,
                                                 int M, int N, int K) {
    __shared__ __align__(16) bf16_t As[128 * 32];
    __shared__ __align__(16) bf16_t Bs[128 * 32];

    int tid = threadIdx.x;
    int lane = tid & 63;
    int wave = tid >> 6;
    int m0 = blockIdx.x * 128;
    int n0 = blockIdx.y * 128;
    int wm = (wave & 1) * 64;
    int wn = (wave >> 1) * 64;
    int col = lane & 15;
    int g = lane >> 4;

    floatx4 acc[4][4] = {};

    // staging: wave w covers rows [w*32, w*32+32) via two 16-row async calls
    int srow = wave * 32 + (lane >> 2);
    int scol = (lane & 3) * 8;
    const bf16_t* Ag = A + (size_t)(m0 + srow) * K + scol;
    const bf16_t* Bg = B + (size_t)(n0 + srow) * K + scol;
    bf16_t* AsW0 = &As[(wave * 2 + 0) * 512];
    bf16_t* AsW1 = &As[(wave * 2 + 1) * 512];
    bf16_t* BsW0 = &Bs[(wave * 2 + 0) * 512];
    bf16_t* BsW1 = &Bs[(wave * 2 + 1) * 512];
    size_t r16 = (size_t)16 * K;

    for (int kk = K >> 5; kk > 0; --kk) {
        __syncthreads();
        gload16(Ag, AsW0);
        gload16(Ag + r16, AsW1);
        gload16(Bg, BsW0);
        gload16(Bg + r16, BsW1);
        Ag += 32; Bg += 32;
        __syncthreads();

        bf16x8 af[4], bfr[4];
#pragma unroll
        for (int i = 0; i < 4; ++i) af[i] = *(const bf16x8*)(&As[(wm + i * 16 + col) * 32 + g * 8]);
#pragma unroll
        for (int j = 0; j < 4; ++j) bfr[j] = *(const bf16x8*)(&Bs[(wn + j * 16 + col) * 32 + g * 8]);
#pragma unroll
        for (int i = 0; i < 4; ++i)
#pragma unroll
            for (int j = 0; j < 4; ++j)
                acc[i][j] = MFMA16(af[i], bfr[j], acc[i][j]);
    }

#pragma unroll
    for (int i = 0; i < 4; ++i)
#pragma unroll
        for (int j = 0; j < 4; ++j) {
            size_t mrow = (size_t)(m0 + wm + i * 16 + g * 4);
            size_t ncol = (size_t)(n0 + wn + j * 16 + col);
            bf16_t* cp = C + mrow * N + ncol;
#pragma unroll
            for (int r = 0; r < 4; ++r) cp[(size_t)r * N] = (bf16_t)acc[i][j][r];
        }
}

// ---------------------------------------------------------------------------
// kv GEMM (m97 staging) with split epilogue:
//   k_nope -> kn[tok][16*128],  v -> vT[b][h][128 d][2048 s]
// ---------------------------------------------------------------------------
__global__ __launch_bounds__(256) void gemm_kv(const bf16_t* __restrict__ A,
                                               const bf16_t* __restrict__ B,
                                               bf16_t* __restrict__ kn,
                                               bf16_t* __restrict__ vT,
                                               int K) {
    __shared__ __align__(16) bf16_t As[128 * 32];
    __shared__ __align__(16) bf16_t Bs[128 * 32];

    int tid = threadIdx.x;
    int lane = tid & 63;
    int wave = tid >> 6;
    int m0 = blockIdx.x * 128;
    int n0 = blockIdx.y * 128;
    int wm = (wave & 1) * 64;
    int wn = (wave >> 1) * 64;
    int col = lane & 15;
    int g = lane >> 4;

    floatx4 acc[4][4] = {};

    int srow = wave * 32 + (lane >> 2);
    int scol = (lane & 3) * 8;
    const bf16_t* Ag = A + (size_t)(m0 + srow) * K + scol;
    const bf16_t* Bg = B + (size_t)(n0 + srow) * K + scol;
    bf16_t* AsW0 = &As[(wave * 2 + 0) * 512];
    bf16_t* AsW1 = &As[(wave * 2 + 1) * 512];
    bf16_t* BsW0 = &Bs[(wave * 2 + 0) * 512];
    bf16_t* BsW1 = &Bs[(wave * 2 + 1) * 512];
    size_t r16 = (size_t)16 * K;

    for (int kk = K >> 5; kk > 0; --kk) {
        __syncthreads();
        gload16(Ag, AsW0);
        gload16(Ag + r16, AsW1);
        gload16(Bg, BsW0);
        gload16(Bg + r16, BsW1);
        Ag += 32; Bg += 32;
        __syncthreads();

        bf16x8 af[4], bfr[4];
#pragma unroll
        for (int i = 0; i < 4; ++i) af[i] = *(const bf16x8*)(&As[(wm + i * 16 + col) * 32 + g * 8]);
#pragma unroll
        for (int j = 0; j < 4; ++j) bfr[j] = *(const bf16x8*)(&Bs[(wn + j * 16 + col) * 32 + g * 8]);
#pragma unroll
        for (int i = 0; i < 4; ++i)
#pragma unroll
            for (int j = 0; j < 4; ++j)
                acc[i][j] = MFMA16(af[i], bfr[j], acc[i][j]);
    }

#pragma unroll
    for (int i = 0; i < 4; ++i)
#pragma unroll
        for (int j = 0; j < 4; ++j) {
            int mrow = m0 + wm + i * 16 + g * 4;
            int ncol = n0 + wn + j * 16 + col;
            int h = ncol >> 8;
            int within = ncol & 255;
            if (within < 128) {
#pragma unroll
                for (int r = 0; r < 4; ++r)
                    kn[(size_t)(mrow + r) * 2048 + h * 128 + within] = (bf16_t)acc[i][j][r];
            } else {
                int d = within - 128;
                int bb = mrow >> 11;
                int s = mrow & 2047;
                bf16x4 pk;
#pragma unroll
                for (int r = 0; r < 4; ++r) pk[r] = (bf16_t)acc[i][j][r];
                *(bf16x4*)(vT + ((size_t)(bb * 16 + h) * 128 + d) * 2048 + s) = pk;
            }
        }
}

// ---------------------------------------------------------------------------
// RMSNorm
// ---------------------------------------------------------------------------
__global__ __launch_bounds__(256) void rmsnorm_kernel(const bf16_t* __restrict__ in, int in_stride,
                                                      const bf16_t* __restrict__ w,
                                                      bf16_t* __restrict__ out, int out_stride,
                                                      int C) {
    int row = blockIdx.x;
    int tid = threadIdx.x;
    const bf16_t* x = in + (size_t)row * in_stride;
    bool act = tid * 8 < C;
    float xs[8];
    float ss = 0.f;
    if (act) {
        bf16x8 v = *(const bf16x8*)(x + tid * 8);
#pragma unroll
        for (int j = 0; j < 8; ++j) {
            xs[j] = (float)v[j];
            ss += xs[j] * xs[j];
        }
    }
    for (int o = 32; o; o >>= 1) ss += __shfl_xor(ss, o, 64);
    __shared__ float red[4];
    if ((tid & 63) == 0) red[tid >> 6] = ss;
    __syncthreads();
    float tot = red[0] + red[1] + red[2] + red[3];
    float scale = rsqrtf(tot / (float)C + 1e-6f);
    if (act) {
        bf16x8 wv = *(const bf16x8*)(w + tid * 8);
        bf16x8 ov;
#pragma unroll
        for (int j = 0; j < 8; ++j) ov[j] = (bf16_t)((float)wv[j] * xs[j] * scale);
        *(bf16x8*)(out + (size_t)row * out_stride + tid * 8) = ov;
    }
}

// ---------------------------------------------------------------------------
// YaRN rope, in place (q_pe of 16 heads + k_pe in ckv).
// ---------------------------------------------------------------------------
__global__ __launch_bounds__(256) void rope_kernel(bf16_t* __restrict__ q,
                                                   bf16_t* __restrict__ ckv,
                                                   const int* __restrict__ pos_ids) {
    int tid = threadIdx.x;
    int lane = tid & 63;
    int gwave = (blockIdx.x * 256 + tid) >> 6;
    int unit = gwave * 2 + ((lane >> 5) & 1);
    int j = lane & 31;
    if (unit >= 4096 * 17) return;
    int t = unit / 17;
    int head = unit % 17;

    float fe = __expf(-(float)j * 0.28782313662425575f);
    float fi = fe * 0.025f;
    float ramp = fminf(fmaxf(((float)j - 10.0f) / 13.0f, 0.0f), 1.0f);
    float invf = fi * ramp + fe * (1.0f - ramp);
    float th = (float)pos_ids[t] * invf;
    float c = cosf(th);
    float s = sinf(th);

    bf16_t* base = (head < 16) ? (q + (size_t)t * 3072 + head * 192 + 128)
                               : (ckv + (size_t)t * 640 + 512);
    float e = (float)base[2 * j];
    float o = (float)base[2 * j + 1];
    base[j] = (bf16_t)(e * c - o * s);
    base[j + 32] = (bf16_t)(o * c + e * s);
}

// ---------------------------------------------------------------------------
// Causal flash attention v6: 8 waves x 16 q rows (512 threads) -> 16 waves/CU
// (4/SIMD) at 2 blocks/CU, 4x the TLP of v5's 1-wave/SIMD regime. Same tile
// count, same staged bytes, same LDS footprint (56 KB). XOR-swizzled LDS,
// 1-tile register prefetch (T14), per-wave Ps sync via lgkmcnt only.
// Block: 128 q x (b,h); k-tile 64. Scale pre-folded in wq_b.
// ---------------------------------------------------------------------------
__global__ __launch_bounds__(512, 4) void attn_kernel(const bf16_t* __restrict__ q,
                                                      const bf16_t* __restrict__ kn,
                                                      const bf16_t* __restrict__ ckv,
                                                      const bf16_t* __restrict__ vT,
                                                      bf16_t* __restrict__ outp) {
    // all tiles XOR-swizzled: 16B chunk index ^= (row & 7)
    __shared__ __align__(16) bf16_t Ks[64][192];    // 64 keys x 192 d
    __shared__ __align__(16) bf16_t Vt[128][64];    // 128 d x 64 keys
    __shared__ __align__(16) bf16_t Ps[8][16][64];  // per-wave P: 16 q x 64 k

    int tid = threadIdx.x;
    int lane = tid & 63;
    int wave = tid >> 6;
    int x = blockIdx.x, y = blockIdx.y;
    // balance hedge: complementary cost under depth-first AND breadth-first dispatch
    int qt0 = x >> 1;
    int qt = (x & 1) ? (15 - qt0) : qt0;
    if (y >= 16) qt = 15 - qt;
    int b = y >> 4;
    int h = y & 15;
    int q0 = qt * 128;
    size_t tok0 = (size_t)b * 2048;
    int col = lane & 15;
    int g = lane >> 4;

    // Q fragments (B operand): q row = q0 + wave*16 + col
    bf16x8 qf[6];
    {
        const bf16_t* qb = q + (tok0 + q0 + wave * 16 + col) * 3072 + h * 192 + g * 8;
#pragma unroll
        for (int ks = 0; ks < 6; ++ks)
            qf[ks] = *(const bf16x8*)(qb + ks * 32);
    }

    // staging geometry (512 threads): K = 64 rows x 24 chunks of 16B (3/thread);
    // V = 128 rows x 8 chunks (2/thread)
    const bf16_t* kg[3]; int kstep[3]; bf16_t* kl[3];
#pragma unroll
    for (int i = 0; i < 3; ++i) {
        int c = tid + i * 512;
        int row = c / 24;
        int ch = c % 24;
        if (ch < 16) { kg[i] = kn + (tok0 + row) * 2048 + h * 128 + ch * 8; kstep[i] = 64 * 2048; }
        else         { kg[i] = ckv + (tok0 + row) * 640 + 512 + (ch - 16) * 8; kstep[i] = 64 * 640; }
        kl[i] = &Ks[row][(ch ^ (row & 7)) * 8];
    }
    const bf16_t* vg[2]; bf16_t* vl[2];
#pragma unroll
    for (int i = 0; i < 2; ++i) {
        int c = tid + i * 512;
        int d = c >> 3;
        int ch = c & 7;
        vg[i] = vT + ((size_t)y * 128 + d) * 2048 + ch * 8;
        vl[i] = &Vt[d][(ch ^ (d & 7)) * 8];
    }

    float m_i = NEG_BIG;
    float l_i = 0.f;
    floatx4 o_acc[8] = {};               // [d m-tile]; col=q, row=d

    char* PsW = (char*)&Ps[wave][0][0];
    int xsw = col & 7;                   // read-side swizzle key (rows mt*16+col)

    // prologue: prefetch tile 0 into registers
    uint4 kpre[3], vpre[2];
#pragma unroll
    for (int i = 0; i < 3; ++i) { kpre[i] = *(const uint4*)kg[i]; kg[i] += kstep[i]; }
#pragma unroll
    for (int i = 0; i < 2; ++i) { vpre[i] = *(const uint4*)vg[i]; vg[i] += 64; }

    int niter = (q0 + 128) >> 6;
    for (int kt = 0; kt < niter; ++kt) {
        int k0 = kt * 64;

        __syncthreads();   // all waves done reading previous tile
#pragma unroll
        for (int i = 0; i < 3; ++i) *(uint4*)kl[i] = kpre[i];
#pragma unroll
        for (int i = 0; i < 2; ++i) *(uint4*)vl[i] = vpre[i];
        __syncthreads();   // tile visible

        // prefetch next tile (hidden under this tile's compute)
        if (kt + 1 < niter) {
#pragma unroll
            for (int i = 0; i < 3; ++i) { kpre[i] = *(const uint4*)kg[i]; kg[i] += kstep[i]; }
#pragma unroll
            for (int i = 0; i < 2; ++i) { vpre[i] = *(const uint4*)vg[i]; vg[i] += 64; }
        }

        // --- S^T: A = K (m=key, 4 tiles), B = Q (n=q, 1 tile of 16)
        floatx4 s_acc[4] = {};
#pragma unroll
        for (int ks = 0; ks < 6; ++ks) {
            bf16x8 ak[4];
#pragma unroll
            for (int mt = 0; mt < 4; ++mt)
                ak[mt] = *(const bf16x8*)(&Ks[mt * 16 + col][((4 * ks + g) ^ xsw) * 8]);
            __builtin_amdgcn_s_setprio(1);
#pragma unroll
            for (int mt = 0; mt < 4; ++mt)
                s_acc[mt] = MFMA16(ak[mt], qf[ks], s_acc[mt]);
            __builtin_amdgcn_s_setprio(0);
        }

        // online softmax: per lane, 16 keys of query (q0 + wave*16 + col)
        {
            int qg = q0 + wave * 16 + col;
            float mx = NEG_BIG;
#pragma unroll
            for (int mt = 0; mt < 4; ++mt)
#pragma unroll
                for (int r = 0; r < 4; ++r) {
                    int key = k0 + mt * 16 + g * 4 + r;
                    float s = (key <= qg) ? s_acc[mt][r] : NEG_BIG;
                    s_acc[mt][r] = s;
                    mx = fmaxf(mx, s);
                }
            mx = fmaxf(mx, __shfl_xor(mx, 16, 64));
            mx = fmaxf(mx, __shfl_xor(mx, 32, 64));
            float mnew = fmaxf(m_i, mx);
            float rs = 0.f;
#pragma unroll
            for (int mt = 0; mt < 4; ++mt) {
                bf16x4 pk;
#pragma unroll
                for (int r = 0; r < 4; ++r) {
                    float p = __expf(s_acc[mt][r] - mnew);
                    rs += p;
                    pk[r] = (bf16_t)p;
                }
                int boff = (col * 128 + mt * 32 + g * 8) ^ ((col & 7) << 4);
                *(bf16x4*)(PsW + boff) = pk;
            }
            rs += __shfl_xor(rs, 16, 64);
            rs += __shfl_xor(rs, 32, 64);
            float alpha = __expf(m_i - mnew);
            l_i = l_i * alpha + rs;
            m_i = mnew;
#pragma unroll
            for (int mt = 0; mt < 8; ++mt)
#pragma unroll
                for (int r = 0; r < 4; ++r)
                    o_acc[mt][r] *= alpha;
        }

        // Ps is per-wave: only this wave's LDS writes need draining, no barrier
        asm volatile("s_waitcnt lgkmcnt(0)" ::: "memory");
        __builtin_amdgcn_sched_barrier(0);

        // --- O^T += V^T (A: m=d, 8 tiles) x P (B: n=q, 1 tile), 64-key contraction
#pragma unroll
        for (int kc = 0; kc < 2; ++kc) {
            bf16x8 bp;
            {
                int boff = (col * 128 + kc * 64 + g * 16) ^ ((col & 7) << 4);
                bp = *(const bf16x8*)(PsW + boff);
            }
#pragma unroll
            for (int mt = 0; mt < 8; ++mt) {
                bf16x8 av = *(const bf16x8*)(&Vt[mt * 16 + col][((4 * kc + g) ^ xsw) * 8]);
                __builtin_amdgcn_s_setprio(1);
                o_acc[mt] = MFMA16(av, bp, o_acc[mt]);
                __builtin_amdgcn_s_setprio(0);
            }
        }
    }

    // epilogue: lane holds d = mt*16 + g*4 + r (4 consecutive) for query col
    {
        float inv = 1.0f / l_i;
        size_t trow = tok0 + q0 + wave * 16 + col;
        bf16_t* op = outp + trow * 2048 + h * 128;
#pragma unroll
        for (int mt = 0; mt < 8; ++mt) {
            bf16x4 pk;
#pragma unroll
            for (int r = 0; r < 4; ++r) pk[r] = (bf16_t)(o_acc[mt][r] * inv);
            *(bf16x4*)(op + mt * 16 + g * 4) = pk;
        }
    }
}

// ---------------------------------------------------------------------------
// Launch
// ---------------------------------------------------------------------------
extern "C" void kernel_launch(void* const* d_in, const int* in_sizes, int n_in,
                              void* d_out, int out_size, void* d_ws, size_t ws_size,
                              hipStream_t stream) {
    const void* hidden_raw = d_in[0];
    const int* pos = (const int*)d_in[1];
    const void* wq_a_raw = d_in[2];
    const void* q_ln_raw = d_in[3];
    const void* wq_b_raw = d_in[4];
    const void* wkv_a_raw = d_in[5];
    const void* kv_ln_raw = d_in[6];
    const void* wkv_b_raw = d_in[7];
    const void* wo_raw = d_in[8];

    char* ws = (char*)d_ws;
    int* flag = (int*)ws;          ws += 256;
    bf16_t* wkv_pad = (bf16_t*)ws; ws += (size_t)640 * 2048 * 2;
    bf16_t* q_a     = (bf16_t*)ws; ws += (size_t)4096 * 1536 * 2;
    bf16_t* qbuf    = (bf16_t*)ws; ws += (size_t)4096 * 3072 * 2;
    bf16_t* ckv     = (bf16_t*)ws; ws += (size_t)4096 * 640 * 2;
    bf16_t* kv_n    = (bf16_t*)ws; ws += (size_t)4096 * 512 * 2;
    bf16_t* knbuf   = (bf16_t*)ws; ws += (size_t)4096 * 2048 * 2;
    bf16_t* vTbuf   = (bf16_t*)ws; ws += (size_t)4096 * 2048 * 2;
    bf16_t* attno   = (bf16_t*)ws; ws += (size_t)4096 * 2048 * 2;
    bf16_t* outbf   = (bf16_t*)ws; ws += (size_t)4096 * 2048 * 2;
    bf16_t* hb      = (bf16_t*)ws; ws += (size_t)4096 * 2048 * 2;
    bf16_t* wqab    = (bf16_t*)ws; ws += (size_t)1536 * 2048 * 2;
    bf16_t* wqbb    = (bf16_t*)ws; ws += (size_t)3072 * 1536 * 2;
    bf16_t* wkvbb   = (bf16_t*)ws; ws += (size_t)4096 * 512 * 2;
    bf16_t* wob     = (bf16_t*)ws; ws += (size_t)2048 * 2048 * 2;
    bf16_t* qlnb    = (bf16_t*)ws; ws += 4096;
    bf16_t* kvlnb   = (bf16_t*)ws; ws += 4096;

    detect_kernel<<<1, 64, 0, stream>>>((const unsigned int*)q_ln_raw, flag);

    // softmax scale folded into wq_b (rope is linear, k_pe unscaled)
    double m = 0.1 * log(40.0) + 1.0;
    float scale = (float)((m * m) / sqrt(192.0));

    conv_in_kernel<<<4096, 256, 0, stream>>>(hidden_raw, hb, (long)4096 * 2048 / 8, flag);
    conv_in_kernel<<<1536, 256, 0, stream>>>(wq_a_raw, wqab, (long)1536 * 2048 / 8, flag);
    conv_in_kernel<<<1, 256, 0, stream>>>(q_ln_raw, qlnb, 1536 / 8, flag);
    conv_in_scale_kernel<<<2304, 256, 0, stream>>>(wq_b_raw, wqbb, (long)3072 * 1536 / 8, flag, scale);
    conv_in_kernel<<<1, 256, 0, stream>>>(kv_ln_raw, kvlnb, 512 / 8, flag);
    conv_in_kernel<<<1024, 256, 0, stream>>>(wkv_b_raw, wkvbb, (long)4096 * 512 / 8, flag);
    conv_in_kernel<<<2048, 256, 0, stream>>>(wo_raw, wob, (long)2048 * 2048 / 8, flag);
    pad_wkv_kernel<<<640, 256, 0, stream>>>(wkv_a_raw, wkv_pad, flag);

    // q_a = hidden @ wq_a^T           (4096 x 1536, K=2048)
    gemm_bf16<<<dim3(32, 12), 256, 0, stream>>>(hb, wqab, q_a, 4096, 1536, 2048);
    // ckv = hidden @ wkv_a_pad^T      (4096 x 640, K=2048)
    gemm_bf16<<<dim3(32, 5), 256, 0, stream>>>(hb, wkv_pad, ckv, 4096, 640, 2048);

    rmsnorm_kernel<<<4096, 256, 0, stream>>>(q_a, 1536, qlnb, q_a, 1536, 1536);
    rmsnorm_kernel<<<4096, 256, 0, stream>>>(ckv, 640, kvlnb, kv_n, 512, 512);

    // q = q_n @ (scale*wq_b)^T        (4096 x 3072, K=1536)
    gemm_bf16<<<dim3(32, 24), 256, 0, stream>>>(q_a, wqbb, qbuf, 4096, 3072, 1536);
    // kv = kv_n @ wkv_b^T, split epilogue (k_nope -> knbuf, v -> vT)
    gemm_kv<<<dim3(32, 32), 256, 0, stream>>>(kv_n, wkvbb, knbuf, vTbuf, 512);

    // rope on q_pe (16 heads) and k_pe (ckv cols 512..575)
    rope_kernel<<<8704, 256, 0, stream>>>(qbuf, ckv, pos);

    attn_kernel<<<dim3(16, 32), 512, 0, stream>>>(qbuf, knbuf, ckv, vTbuf, attno);

    // out = attno @ wo^T              (4096 x 2048, K=2048)
    gemm_bf16<<<dim3(32, 16), 256, 0, stream>>>(attno, wob, outbf, 4096, 2048, 2048);

    conv_out_kernel<<<4096, 256, 0, stream>>>(outbf, d_out, (long)4096 * 2048 / 8, flag);
}

// Round 4
// 511.292 us; speedup vs baseline: 1.3411x; 1.0836x over previous
//
#include <hip/hip_runtime.h>
#include <hip/hip_bf16.h>
#include <math.h>

typedef __bf16 bf16_t;
typedef __bf16 bf16x4 __attribute__((ext_vector_type(4)));
typedef __bf16 bf16x8 __attribute__((ext_vector_type(8)));
typedef float floatx4 __attribute__((ext_vector_type(4)));

#define MFMA16(a, b, c) __builtin_amdgcn_mfma_f32_16x16x32_bf16((a), (b), (c), 0, 0, 0)

#define NEG_BIG (-1e30f)

// async global->LDS, 16B per lane; lds dest = wave-uniform base + lane*16
__device__ __forceinline__ void gload16(const bf16_t* g, bf16_t* l) {
    __builtin_amdgcn_global_load_lds(
        (const __attribute__((address_space(1))) unsigned int*)g,
        (__attribute__((address_space(3))) unsigned int*)l,
        16, 0, 0);
}

// ---------------------------------------------------------------------------
// Detect input dtype: q_a_ln_w is all ones. fp32 word0 = 0x3F800000,
// bf16-packed word0 = 0x3F803F80. flag=1 -> bf16, flag=0 -> fp32.
// ---------------------------------------------------------------------------
__global__ void detect_kernel(const unsigned int* __restrict__ lnw, int* __restrict__ flag) {
    if (threadIdx.x == 0 && blockIdx.x == 0)
        flag[0] = (lnw[0] == 0x3F803F80u) ? 1 : 0;
}

__global__ __launch_bounds__(256) void conv_in_kernel(const void* __restrict__ src,
                                                      bf16_t* __restrict__ dst,
                                                      long nchunk,
                                                      const int* __restrict__ flag) {
    long i = (long)blockIdx.x * 256 + threadIdx.x;
    if (i >= nchunk) return;
    if (flag[0]) {
        ((uint4*)dst)[i] = ((const uint4*)src)[i];
    } else {
        const float* f = (const float*)src + i * 8;
        bf16x8 o;
#pragma unroll
        for (int j = 0; j < 8; ++j) o[j] = (bf16_t)f[j];
        ((bf16x8*)dst)[i] = o;
    }
}

// conv with scalar multiply (used to fold softmax scale into wq_b)
__global__ __launch_bounds__(256) void conv_in_scale_kernel(const void* __restrict__ src,
                                                            bf16_t* __restrict__ dst,
                                                            long nchunk,
                                                            const int* __restrict__ flag,
                                                            float s) {
    long i = (long)blockIdx.x * 256 + threadIdx.x;
    if (i >= nchunk) return;
    bf16x8 o;
    if (flag[0]) {
        bf16x8 v = ((const bf16x8*)src)[i];
#pragma unroll
        for (int j = 0; j < 8; ++j) o[j] = (bf16_t)((float)v[j] * s);
    } else {
        const float* f = (const float*)src + i * 8;
#pragma unroll
        for (int j = 0; j < 8; ++j) o[j] = (bf16_t)(f[j] * s);
    }
    ((bf16x8*)dst)[i] = o;
}

__global__ __launch_bounds__(256) void conv_out_kernel(const bf16_t* __restrict__ src,
                                                       void* __restrict__ dst,
                                                       long nchunk,
                                                       const int* __restrict__ flag) {
    long i = (long)blockIdx.x * 256 + threadIdx.x;
    if (i >= nchunk) return;
    bf16x8 v = ((const bf16x8*)src)[i];
    if (flag[0]) {
        ((uint4*)dst)[i] = *(const uint4*)&v;
    } else {
        float* f = (float*)dst + i * 8;
#pragma unroll
        for (int j = 0; j < 8; ++j) f[j] = (float)v[j];
    }
}

__global__ __launch_bounds__(256) void pad_wkv_kernel(const void* __restrict__ src,
                                                      bf16_t* __restrict__ dst,
                                                      const int* __restrict__ flag) {
    long idx = (long)blockIdx.x * 256 + threadIdx.x;
    long e0 = idx * 8;
    if (e0 >= (long)640 * 2048) return;
    int row = (int)(e0 >> 11);
    bf16x8 v;
#pragma unroll
    for (int j = 0; j < 8; ++j) v[j] = (bf16_t)0.0f;
    if (row < 576) {
        if (flag[0]) {
            v = *(const bf16x8*)((const bf16_t*)src + e0);
        } else {
            const float* f = (const float*)src + e0;
#pragma unroll
            for (int j = 0; j < 8; ++j) v[j] = (bf16_t)f[j];
        }
    }
    *(bf16x8*)(dst + e0) = v;
}

// ---------------------------------------------------------------------------
// GEMM v2: m97 tile (128x128, BK=32) + T4 counted-vmcnt double-buffer.
// Raw s_barrier (no vmcnt(0)/lgkmcnt(0) drain); per-wave vmcnt(4) before the
// pre-compute barrier guarantees the incoming tile's 4 loads landed for every
// wave (tile kt+1's 4 loads stay in flight across the barrier). Source-side
// chunk-XOR swizzle (rule 21: linear LDS dest, pre-swizzled global source,
// swizzled read) halves the 8-way ds_read conflict.
// ---------------------------------------------------------------------------
#define GEMM_STAGE(bufsel) do { \
        gload16(Ag, &As[bufsel][(wave * 2 + 0) * 512]); \
        gload16(Ag + r16, &As[bufsel][(wave * 2 + 1) * 512]); \
        gload16(Bg, &Bs[bufsel][(wave * 2 + 0) * 512]); \
        gload16(Bg + r16, &Bs[bufsel][(wave * 2 + 1) * 512]); \
        Ag += 32; Bg += 32; } while (0)

#define GEMM_PIPELINE_BODY \
    int tid = threadIdx.x; \
    int lane = tid & 63; \
    int wave = tid >> 6; \
    int m0 = blockIdx.x * 128; \
    int n0 = blockIdx.y * 128; \
    int wm = (wave & 1) * 64; \
    int wn = (wave >> 1) * 64; \
    int col = lane & 15; \
    int g = lane >> 4; \
    floatx4 acc[4][4] = {}; \
    int srow = wave * 32 + (lane >> 2); \
    int scol = ((lane & 3) ^ (srow & 3)) * 8; \
    const bf16_t* Ag = A + (size_t)(m0 + srow) * K + scol; \
    const bf16_t* Bg = B + (size_t)(n0 + srow) * K + scol; \
    size_t r16 = (size_t)16 * K; \
    int rchunk = (g ^ (col & 3)) * 8; \
    int nk = K >> 5; \
    GEMM_STAGE(0); \
    GEMM_STAGE(1); \
    int cur = 0; \
    for (int kt = 0; kt < nk; ++kt) { \
        if (kt + 1 < nk) asm volatile("s_waitcnt vmcnt(4)" ::: "memory"); \
        else             asm volatile("s_waitcnt vmcnt(0)" ::: "memory"); \
        __builtin_amdgcn_s_barrier(); \
        __builtin_amdgcn_sched_barrier(0); \
        bf16x8 af[4], bfr[4]; \
        _Pragma("unroll") \
        for (int i = 0; i < 4; ++i) af[i] = *(const bf16x8*)(&As[cur][(wm + i * 16 + col) * 32 + rchunk]); \
        _Pragma("unroll") \
        for (int j = 0; j < 4; ++j) bfr[j] = *(const bf16x8*)(&Bs[cur][(wn + j * 16 + col) * 32 + rchunk]); \
        _Pragma("unroll") \
        for (int i = 0; i < 4; ++i) \
            _Pragma("unroll") \
            for (int j = 0; j < 4; ++j) \
                acc[i][j] = MFMA16(af[i], bfr[j], acc[i][j]); \
        __builtin_amdgcn_sched_barrier(0); \
        __builtin_amdgcn_s_barrier(); \
        if (kt + 2 < nk) { GEMM_STAGE(cur); } \
        cur ^= 1; \
    }

__global__ __launch_bounds__(256) void gemm_bf16(const bf16_t* __restrict__ A,
                                                 const bf16_t* __restrict__ B,
                                                 bf16_t* __restrict__ C,
                                                 int M, int N, int K) {
    __shared__ __align__(16) bf16_t As[2][128 * 32];
    __shared__ __align__(16) bf16_t Bs[2][128 * 32];
    GEMM_PIPELINE_BODY

#pragma unroll
    for (int i = 0; i < 4; ++i)
#pragma unroll
        for (int j = 0; j < 4; ++j) {
            size_t mrow = (size_t)(m0 + wm + i * 16 + g * 4);
            size_t ncol = (size_t)(n0 + wn + j * 16 + col);
            bf16_t* cp = C + mrow * N + ncol;
#pragma unroll
            for (int r = 0; r < 4; ++r) cp[(size_t)r * N] = (bf16_t)acc[i][j][r];
        }
}

// kv GEMM: same pipeline, split epilogue (k_nope -> kn, v -> vT)
__global__ __launch_bounds__(256) void gemm_kv(const bf16_t* __restrict__ A,
                                               const bf16_t* __restrict__ B,
                                               bf16_t* __restrict__ kn,
                                               bf16_t* __restrict__ vT,
                                               int K) {
    __shared__ __align__(16) bf16_t As[2][128 * 32];
    __shared__ __align__(16) bf16_t Bs[2][128 * 32];
    GEMM_PIPELINE_BODY

#pragma unroll
    for (int i = 0; i < 4; ++i)
#pragma unroll
        for (int j = 0; j < 4; ++j) {
            int mrow = m0 + wm + i * 16 + g * 4;
            int ncol = n0 + wn + j * 16 + col;
            int h = ncol >> 8;
            int within = ncol & 255;
            if (within < 128) {
#pragma unroll
                for (int r = 0; r < 4; ++r)
                    kn[(size_t)(mrow + r) * 2048 + h * 128 + within] = (bf16_t)acc[i][j][r];
            } else {
                int d = within - 128;
                int bb = mrow >> 11;
                int s = mrow & 2047;
                bf16x4 pk;
#pragma unroll
                for (int r = 0; r < 4; ++r) pk[r] = (bf16_t)acc[i][j][r];
                *(bf16x4*)(vT + ((size_t)(bb * 16 + h) * 128 + d) * 2048 + s) = pk;
            }
        }
}

// ---------------------------------------------------------------------------
// RMSNorm
// ---------------------------------------------------------------------------
__global__ __launch_bounds__(256) void rmsnorm_kernel(const bf16_t* __restrict__ in, int in_stride,
                                                      const bf16_t* __restrict__ w,
                                                      bf16_t* __restrict__ out, int out_stride,
                                                      int C) {
    int row = blockIdx.x;
    int tid = threadIdx.x;
    const bf16_t* x = in + (size_t)row * in_stride;
    bool act = tid * 8 < C;
    float xs[8];
    float ss = 0.f;
    if (act) {
        bf16x8 v = *(const bf16x8*)(x + tid * 8);
#pragma unroll
        for (int j = 0; j < 8; ++j) {
            xs[j] = (float)v[j];
            ss += xs[j] * xs[j];
        }
    }
    for (int o = 32; o; o >>= 1) ss += __shfl_xor(ss, o, 64);
    __shared__ float red[4];
    if ((tid & 63) == 0) red[tid >> 6] = ss;
    __syncthreads();
    float tot = red[0] + red[1] + red[2] + red[3];
    float scale = rsqrtf(tot / (float)C + 1e-6f);
    if (act) {
        bf16x8 wv = *(const bf16x8*)(w + tid * 8);
        bf16x8 ov;
#pragma unroll
        for (int j = 0; j < 8; ++j) ov[j] = (bf16_t)((float)wv[j] * xs[j] * scale);
        *(bf16x8*)(out + (size_t)row * out_stride + tid * 8) = ov;
    }
}

// ---------------------------------------------------------------------------
// YaRN rope, in place (q_pe of 16 heads + k_pe in ckv).
// ---------------------------------------------------------------------------
__global__ __launch_bounds__(256) void rope_kernel(bf16_t* __restrict__ q,
                                                   bf16_t* __restrict__ ckv,
                                                   const int* __restrict__ pos_ids) {
    int tid = threadIdx.x;
    int lane = tid & 63;
    int gwave = (blockIdx.x * 256 + tid) >> 6;
    int unit = gwave * 2 + ((lane >> 5) & 1);
    int j = lane & 31;
    if (unit >= 4096 * 17) return;
    int t = unit / 17;
    int head = unit % 17;

    float fe = __expf(-(float)j * 0.28782313662425575f);
    float fi = fe * 0.025f;
    float ramp = fminf(fmaxf(((float)j - 10.0f) / 13.0f, 0.0f), 1.0f);
    float invf = fi * ramp + fe * (1.0f - ramp);
    float th = (float)pos_ids[t] * invf;
    float c = cosf(th);
    float s = sinf(th);

    bf16_t* base = (head < 16) ? (q + (size_t)t * 3072 + head * 192 + 128)
                               : (ckv + (size_t)t * 640 + 512);
    float e = (float)base[2 * j];
    float o = (float)base[2 * j + 1];
    base[j] = (bf16_t)(e * c - o * s);
    base[j + 32] = (bf16_t)(o * c + e * s);
}

// ---------------------------------------------------------------------------
// Causal flash attention v7: v6 structure (8 waves x 16 q, 512 threads,
// XOR-swizzled LDS, 1-tile register prefetch) + instruction cuts:
//   - interior tiles skip the causal-mask cndmask chain (wave-uniform test)
//   - T13 defer-max (THR=8): skip o_acc rescale when max doesn't grow
//   - fully-masked trailing tiles skip compute entirely (wave-uniform)
// ---------------------------------------------------------------------------
__global__ __launch_bounds__(512, 4) void attn_kernel(const bf16_t* __restrict__ q,
                                                      const bf16_t* __restrict__ kn,
                                                      const bf16_t* __restrict__ ckv,
                                                      const bf16_t* __restrict__ vT,
                                                      bf16_t* __restrict__ outp) {
    // all tiles XOR-swizzled: 16B chunk index ^= (row & 7)
    __shared__ __align__(16) bf16_t Ks[64][192];    // 64 keys x 192 d
    __shared__ __align__(16) bf16_t Vt[128][64];    // 128 d x 64 keys
    __shared__ __align__(16) bf16_t Ps[8][16][64];  // per-wave P: 16 q x 64 k

    int tid = threadIdx.x;
    int lane = tid & 63;
    int wave = tid >> 6;
    int x = blockIdx.x, y = blockIdx.y;
    // balance hedge: complementary cost under depth-first AND breadth-first dispatch
    int qt0 = x >> 1;
    int qt = (x & 1) ? (15 - qt0) : qt0;
    if (y >= 16) qt = 15 - qt;
    int b = y >> 4;
    int h = y & 15;
    int q0 = qt * 128;
    size_t tok0 = (size_t)b * 2048;
    int col = lane & 15;
    int g = lane >> 4;

    // Q fragments (B operand): q row = q0 + wave*16 + col
    bf16x8 qf[6];
    {
        const bf16_t* qb = q + (tok0 + q0 + wave * 16 + col) * 3072 + h * 192 + g * 8;
#pragma unroll
        for (int ks = 0; ks < 6; ++ks)
            qf[ks] = *(const bf16x8*)(qb + ks * 32);
    }

    // staging geometry (512 threads): K = 64 rows x 24 chunks of 16B (3/thread);
    // V = 128 rows x 8 chunks (2/thread)
    const bf16_t* kg[3]; int kstep[3]; bf16_t* kl[3];
#pragma unroll
    for (int i = 0; i < 3; ++i) {
        int c = tid + i * 512;
        int row = c / 24;
        int ch = c % 24;
        if (ch < 16) { kg[i] = kn + (tok0 + row) * 2048 + h * 128 + ch * 8; kstep[i] = 64 * 2048; }
        else         { kg[i] = ckv + (tok0 + row) * 640 + 512 + (ch - 16) * 8; kstep[i] = 64 * 640; }
        kl[i] = &Ks[row][(ch ^ (row & 7)) * 8];
    }
    const bf16_t* vg[2]; bf16_t* vl[2];
#pragma unroll
    for (int i = 0; i < 2; ++i) {
        int c = tid + i * 512;
        int d = c >> 3;
        int ch = c & 7;
        vg[i] = vT + ((size_t)y * 128 + d) * 2048 + ch * 8;
        vl[i] = &Vt[d][(ch ^ (d & 7)) * 8];
    }

    float m_i = NEG_BIG;
    float l_i = 0.f;
    floatx4 o_acc[8] = {};               // [d m-tile]; col=q, row=d

    char* PsW = (char*)&Ps[wave][0][0];
    int xsw = col & 7;                   // read-side swizzle key (rows mt*16+col)

    // prologue: prefetch tile 0 into registers
    uint4 kpre[3], vpre[2];
#pragma unroll
    for (int i = 0; i < 3; ++i) { kpre[i] = *(const uint4*)kg[i]; kg[i] += kstep[i]; }
#pragma unroll
    for (int i = 0; i < 2; ++i) { vpre[i] = *(const uint4*)vg[i]; vg[i] += 64; }

    int niter = (q0 + 128) >> 6;
    for (int kt = 0; kt < niter; ++kt) {
        int k0 = kt * 64;

        __syncthreads();   // all waves done reading previous tile
#pragma unroll
        for (int i = 0; i < 3; ++i) *(uint4*)kl[i] = kpre[i];
#pragma unroll
        for (int i = 0; i < 2; ++i) *(uint4*)vl[i] = vpre[i];
        __syncthreads();   // tile visible

        // prefetch next tile (hidden under this tile's compute)
        if (kt + 1 < niter) {
#pragma unroll
            for (int i = 0; i < 3; ++i) { kpre[i] = *(const uint4*)kg[i]; kg[i] += kstep[i]; }
#pragma unroll
            for (int i = 0; i < 2; ++i) { vpre[i] = *(const uint4*)vg[i]; vg[i] += 64; }
        }

        // fully-masked tiles for this wave: skip all compute (barriers stay hit)
        if (k0 > q0 + wave * 16 + 15) continue;

        // --- S^T: A = K (m=key, 4 tiles), B = Q (n=q, 1 tile of 16)
        floatx4 s_acc[4] = {};
#pragma unroll
        for (int ks = 0; ks < 6; ++ks) {
            bf16x8 ak[4];
#pragma unroll
            for (int mt = 0; mt < 4; ++mt)
                ak[mt] = *(const bf16x8*)(&Ks[mt * 16 + col][((4 * ks + g) ^ xsw) * 8]);
            __builtin_amdgcn_s_setprio(1);
#pragma unroll
            for (int mt = 0; mt < 4; ++mt)
                s_acc[mt] = MFMA16(ak[mt], qf[ks], s_acc[mt]);
            __builtin_amdgcn_s_setprio(0);
        }

        // online softmax: per lane, 16 keys of query (q0 + wave*16 + col)
        {
            int qg = q0 + wave * 16 + col;
            float mx = NEG_BIG;
            if (k0 + 63 > q0 + wave * 16) {
                // boundary tile: apply causal mask
#pragma unroll
                for (int mt = 0; mt < 4; ++mt)
#pragma unroll
                    for (int r = 0; r < 4; ++r) {
                        int key = k0 + mt * 16 + g * 4 + r;
                        float s = (key <= qg) ? s_acc[mt][r] : NEG_BIG;
                        s_acc[mt][r] = s;
                        mx = fmaxf(mx, s);
                    }
            } else {
                // interior tile: no masking needed
#pragma unroll
                for (int mt = 0; mt < 4; ++mt)
#pragma unroll
                    for (int r = 0; r < 4; ++r) mx = fmaxf(mx, s_acc[mt][r]);
            }
            mx = fmaxf(mx, __shfl_xor(mx, 16, 64));
            mx = fmaxf(mx, __shfl_xor(mx, 32, 64));
            // T13 defer-max: keep old max while growth <= 8 (P bounded by e^8)
            bool defer = __all(mx <= m_i + 8.0f);
            float mnew = defer ? m_i : fmaxf(m_i, mx);
            float rs = 0.f;
#pragma unroll
            for (int mt = 0; mt < 4; ++mt) {
                bf16x4 pk;
#pragma unroll
                for (int r = 0; r < 4; ++r) {
                    float p = __expf(s_acc[mt][r] - mnew);
                    rs += p;
                    pk[r] = (bf16_t)p;
                }
                int boff = (col * 128 + mt * 32 + g * 8) ^ ((col & 7) << 4);
                *(bf16x4*)(PsW + boff) = pk;
            }
            rs += __shfl_xor(rs, 16, 64);
            rs += __shfl_xor(rs, 32, 64);
            if (defer) {
                l_i += rs;
            } else {
                float alpha = __expf(m_i - mnew);
                l_i = l_i * alpha + rs;
                m_i = mnew;
#pragma unroll
                for (int mt = 0; mt < 8; ++mt)
#pragma unroll
                    for (int r = 0; r < 4; ++r)
                        o_acc[mt][r] *= alpha;
            }
        }

        // Ps is per-wave: only this wave's LDS writes need draining, no barrier
        asm volatile("s_waitcnt lgkmcnt(0)" ::: "memory");
        __builtin_amdgcn_sched_barrier(0);

        // --- O^T += V^T (A: m=d, 8 tiles) x P (B: n=q, 1 tile), 64-key contraction
#pragma unroll
        for (int kc = 0; kc < 2; ++kc) {
            bf16x8 bp;
            {
                int boff = (col * 128 + kc * 64 + g * 16) ^ ((col & 7) << 4);
                bp = *(const bf16x8*)(PsW + boff);
            }
#pragma unroll
            for (int mt = 0; mt < 8; ++mt) {
                bf16x8 av = *(const bf16x8*)(&Vt[mt * 16 + col][((4 * kc + g) ^ xsw) * 8]);
                __builtin_amdgcn_s_setprio(1);
                o_acc[mt] = MFMA16(av, bp, o_acc[mt]);
                __builtin_amdgcn_s_setprio(0);
            }
        }
    }

    // epilogue: lane holds d = mt*16 + g*4 + r (4 consecutive) for query col
    {
        float inv = 1.0f / l_i;
        size_t trow = tok0 + q0 + wave * 16 + col;
        bf16_t* op = outp + trow * 2048 + h * 128;
#pragma unroll
        for (int mt = 0; mt < 8; ++mt) {
            bf16x4 pk;
#pragma unroll
            for (int r = 0; r < 4; ++r) pk[r] = (bf16_t)(o_acc[mt][r] * inv);
            *(bf16x4*)(op + mt * 16 + g * 4) = pk;
        }
    }
}

// ---------------------------------------------------------------------------
// Launch
// ---------------------------------------------------------------------------
extern "C" void kernel_launch(void* const* d_in, const int* in_sizes, int n_in,
                              void* d_out, int out_size, void* d_ws, size_t ws_size,
                              hipStream_t stream) {
    const void* hidden_raw = d_in[0];
    const int* pos = (const int*)d_in[1];
    const void* wq_a_raw = d_in[2];
    const void* q_ln_raw = d_in[3];
    const void* wq_b_raw = d_in[4];
    const void* wkv_a_raw = d_in[5];
    const void* kv_ln_raw = d_in[6];
    const void* wkv_b_raw = d_in[7];
    const void* wo_raw = d_in[8];

    char* ws = (char*)d_ws;
    int* flag = (int*)ws;          ws += 256;
    bf16_t* wkv_pad = (bf16_t*)ws; ws += (size_t)640 * 2048 * 2;
    bf16_t* q_a     = (bf16_t*)ws; ws += (size_t)4096 * 1536 * 2;
    bf16_t* qbuf    = (bf16_t*)ws; ws += (size_t)4096 * 3072 * 2;
    bf16_t* ckv     = (bf16_t*)ws; ws += (size_t)4096 * 640 * 2;
    bf16_t* kv_n    = (bf16_t*)ws; ws += (size_t)4096 * 512 * 2;
    bf16_t* knbuf   = (bf16_t*)ws; ws += (size_t)4096 * 2048 * 2;
    bf16_t* vTbuf   = (bf16_t*)ws; ws += (size_t)4096 * 2048 * 2;
    bf16_t* attno   = (bf16_t*)ws; ws += (size_t)4096 * 2048 * 2;
    bf16_t* outbf   = (bf16_t*)ws; ws += (size_t)4096 * 2048 * 2;
    bf16_t* hb      = (bf16_t*)ws; ws += (size_t)4096 * 2048 * 2;
    bf16_t* wqab    = (bf16_t*)ws; ws += (size_t)1536 * 2048 * 2;
    bf16_t* wqbb    = (bf16_t*)ws; ws += (size_t)3072 * 1536 * 2;
    bf16_t* wkvbb   = (bf16_t*)ws; ws += (size_t)4096 * 512 * 2;
    bf16_t* wob     = (bf16_t*)ws; ws += (size_t)2048 * 2048 * 2;
    bf16_t* qlnb    = (bf16_t*)ws; ws += 4096;
    bf16_t* kvlnb   = (bf16_t*)ws; ws += 4096;

    detect_kernel<<<1, 64, 0, stream>>>((const unsigned int*)q_ln_raw, flag);

    // softmax scale folded into wq_b (rope is linear, k_pe unscaled)
    double m = 0.1 * log(40.0) + 1.0;
    float scale = (float)((m * m) / sqrt(192.0));

    conv_in_kernel<<<4096, 256, 0, stream>>>(hidden_raw, hb, (long)4096 * 2048 / 8, flag);
    conv_in_kernel<<<1536, 256, 0, stream>>>(wq_a_raw, wqab, (long)1536 * 2048 / 8, flag);
    conv_in_kernel<<<1, 256, 0, stream>>>(q_ln_raw, qlnb, 1536 / 8, flag);
    conv_in_scale_kernel<<<2304, 256, 0, stream>>>(wq_b_raw, wqbb, (long)3072 * 1536 / 8, flag, scale);
    conv_in_kernel<<<1, 256, 0, stream>>>(kv_ln_raw, kvlnb, 512 / 8, flag);
    conv_in_kernel<<<1024, 256, 0, stream>>>(wkv_b_raw, wkvbb, (long)4096 * 512 / 8, flag);
    conv_in_kernel<<<2048, 256, 0, stream>>>(wo_raw, wob, (long)2048 * 2048 / 8, flag);
    pad_wkv_kernel<<<640, 256, 0, stream>>>(wkv_a_raw, wkv_pad, flag);

    // q_a = hidden @ wq_a^T           (4096 x 1536, K=2048)
    gemm_bf16<<<dim3(32, 12), 256, 0, stream>>>(hb, wqab, q_a, 4096, 1536, 2048);
    // ckv = hidden @ wkv_a_pad^T      (4096 x 640, K=2048)
    gemm_bf16<<<dim3(32, 5), 256, 0, stream>>>(hb, wkv_pad, ckv, 4096, 640, 2048);

    rmsnorm_kernel<<<4096, 256, 0, stream>>>(q_a, 1536, qlnb, q_a, 1536, 1536);
    rmsnorm_kernel<<<4096, 256, 0, stream>>>(ckv, 640, kvlnb, kv_n, 512, 512);

    // q = q_n @ (scale*wq_b)^T        (4096 x 3072, K=1536)
    gemm_bf16<<<dim3(32, 24), 256, 0, stream>>>(q_a, wqbb, qbuf, 4096, 3072, 1536);
    // kv = kv_n @ wkv_b^T, split epilogue (k_nope -> knbuf, v -> vT)
    gemm_kv<<<dim3(32, 32), 256, 0, stream>>>(kv_n, wkvbb, knbuf, vTbuf, 512);

    // rope on q_pe (16 heads) and k_pe (ckv cols 512..575)
    rope_kernel<<<8704, 256, 0, stream>>>(qbuf, ckv, pos);

    attn_kernel<<<dim3(16, 32), 512, 0, stream>>>(qbuf, knbuf, ckv, vTbuf, attno);

    // out = attno @ wo^T              (4096 x 2048, K=2048)
    gemm_bf16<<<dim3(32, 16), 256, 0, stream>>>(attno, wob, outbf, 4096, 2048, 2048);

    conv_out_kernel<<<4096, 256, 0, stream>>>(outbf, d_out, (long)4096 * 2048 / 8, flag);
}